// Round 14
// baseline (502.849 us; speedup 1.0000x reference)
//
#include <hip/hip_runtime.h>

#define TSTEPS 20
#define THRESV 1.0f
#define DECAYV 0.9375f

typedef float f32x4 __attribute__((ext_vector_type(4)));

// W2 raw group partials, parity double-buffered: [par][slice][group][col]
__device__ float g_P[2][64][32][128];

// ws layout (bytes):
//   [0      .. 32768)   float m1[8192]
//   [32768  .. 65536)   float m2[8192]
//   [65536  .. 65600)   float m3[16]
//   [65600  .. 73280)   u64 s_in_bits[20][48]
//   [73280  .. 93760)   u64 s1_bits[20][128]
//   [93760  .. 114240)  u64 s2_bits[20][128]

__global__ void snn_input_kernel(const float* __restrict__ image,
                                 unsigned long long* __restrict__ s_in_bits) {
    int i = blockIdx.x * 256 + threadIdx.x;   // 0..3071
    float img = image[i];
    float mi = 0.f;
    int word = i >> 6, lane = i & 63;
    for (int t = 0; t < TSTEPS; ++t) {
        mi += img;
        bool fire = (mi >= THRESV);
        if (fire) mi -= THRESV;
        unsigned long long bm = __ballot(fire);
        if (lane == 0) s_in_bits[t * 48 + word] = bm;
    }
}

struct __align__(16) SMem {
    unsigned short list[8192];      // 16 KiB compacted firing-row indices
    float partials[4096];           // 16 KiB [32][128] (W1 epilogue / W3)
    unsigned long long bw[128];
    unsigned pc[128];
    int cntp;
};

// Deterministic parallel compaction (ascending list order, bitwise-stable).
template <int NW>
__device__ __forceinline__ int compact_par(const unsigned long long* bits, SMem& sm) {
    int tid = threadIdx.x;
    if (tid < NW) {
        unsigned long long w = bits ? bits[tid] : 0ULL;
        sm.bw[tid] = w;
        sm.pc[tid] = (unsigned)__popcll(w);
    }
    __syncthreads();
    constexpr int WPW = NW / 8;
    int wave = tid >> 6, lane = tid & 63;
    int w0 = wave * WPW;
    int base = 0;
    for (int i = lane; i < w0; i += 64) base += (int)sm.pc[i];
    #pragma unroll
    for (int off = 1; off < 64; off <<= 1) base += __shfl_xor(base, off);
    if (wave == 0) {
        int tot = 0;
        for (int i = lane; i < NW; i += 64) tot += (int)sm.pc[i];
        #pragma unroll
        for (int off = 1; off < 64; off <<= 1) tot += __shfl_xor(tot, off);
        if (lane == 0) sm.cntp = tot;
    }
    for (int i = 0; i < WPW; ++i) {
        unsigned long long w = sm.bw[w0 + i];
        if ((w >> lane) & 1ull) {
            int pos = base + __popcll(w & ((1ull << lane) - 1ull));
            sm.list[pos] = (unsigned short)(((w0 + i) << 6) + lane);
        }
        base += __popcll(w);
    }
    __syncthreads();
    return sm.cntp;
}

#define GLD(dst, ptr) \
    asm volatile("global_load_dwordx4 %0, %1, off" : "=v"(dst) : "v"(ptr))
#define WAIT8(a0,a1,a2,a3,a4,a5,a6,a7) \
    asm volatile("s_waitcnt vmcnt(0)" \
        : "+v"(a0),"+v"(a1),"+v"(a2),"+v"(a3),"+v"(a4),"+v"(a5),"+v"(a6),"+v"(a7))
#define WAIT4(a0,a1,a2,a3) \
    asm volatile("s_waitcnt vmcnt(0)" : "+v"(a0),"+v"(a1),"+v"(a2),"+v"(a3))

// ---- W1: 128-col slice, 512B chunks, dual chains (g, g+16), LIF epilogue.
// r12 gather_lif128 verbatim: per-(col,group) chain = ascending k (mod 32),
// reduce ascending gg 0..31 => bitwise-identical sums.
__device__ __forceinline__ void gather_lif128(const float* __restrict__ W, int colbase,
                                              int count, SMem& sm,
                                              float* __restrict__ m, int mbase,
                                              unsigned long long* __restrict__ dst_words) {
    int tid = threadIdx.x;
    int c = tid & 31, g = tid >> 5;                  // c 0..31, g 0..15
    const float* base = W + (size_t)colbase + (size_t)c * 4;
    float ax = 0.f, ay = 0.f, az = 0.f, aw = 0.f;    // chain A (group g)
    float bx = 0.f, by = 0.f, bz = 0.f, bw_ = 0.f;   // chain B (group g+16)
    int k = g;
    for (; k + 112 < count; k += 128) {
        const float* pa0 = base + (size_t)sm.list[k      ] * 8192;
        const float* pa1 = base + (size_t)sm.list[k + 32 ] * 8192;
        const float* pa2 = base + (size_t)sm.list[k + 64 ] * 8192;
        const float* pa3 = base + (size_t)sm.list[k + 96 ] * 8192;
        const float* pb0 = base + (size_t)sm.list[k + 16 ] * 8192;
        const float* pb1 = base + (size_t)sm.list[k + 48 ] * 8192;
        const float* pb2 = base + (size_t)sm.list[k + 80 ] * 8192;
        const float* pb3 = base + (size_t)sm.list[k + 112] * 8192;
        f32x4 a0, a1, a2, a3, b0, b1, b2, b3;
        GLD(a0, pa0); GLD(b0, pb0); GLD(a1, pa1); GLD(b1, pb1);
        GLD(a2, pa2); GLD(b2, pb2); GLD(a3, pa3); GLD(b3, pb3);
        WAIT8(a0, b0, a1, b1, a2, b2, a3, b3);
        ax += a0.x; ay += a0.y; az += a0.z; aw += a0.w;
        ax += a1.x; ay += a1.y; az += a1.z; aw += a1.w;
        ax += a2.x; ay += a2.y; az += a2.z; aw += a2.w;
        ax += a3.x; ay += a3.y; az += a3.z; aw += a3.w;
        bx += b0.x; by += b0.y; bz += b0.z; bw_ += b0.w;
        bx += b1.x; by += b1.y; bz += b1.z; bw_ += b1.w;
        bx += b2.x; by += b2.y; bz += b2.z; bw_ += b2.w;
        bx += b3.x; by += b3.y; bz += b3.z; bw_ += b3.w;
    }
    for (; k + 48 < count; k += 64) {
        const float* pa0 = base + (size_t)sm.list[k     ] * 8192;
        const float* pa1 = base + (size_t)sm.list[k + 32] * 8192;
        const float* pb0 = base + (size_t)sm.list[k + 16] * 8192;
        const float* pb1 = base + (size_t)sm.list[k + 48] * 8192;
        f32x4 a0, a1, b0, b1;
        GLD(a0, pa0); GLD(b0, pb0); GLD(a1, pa1); GLD(b1, pb1);
        WAIT4(a0, b0, a1, b1);
        ax += a0.x; ay += a0.y; az += a0.z; aw += a0.w;
        ax += a1.x; ay += a1.y; az += a1.z; aw += a1.w;
        bx += b0.x; by += b0.y; bz += b0.z; bw_ += b0.w;
        bx += b1.x; by += b1.y; bz += b1.z; bw_ += b1.w;
    }
    for (; k < count; k += 32) {
        f32x4 va = *(const f32x4*)(base + (size_t)sm.list[k] * 8192);
        ax += va.x; ay += va.y; az += va.z; aw += va.w;
        if (k + 16 < count) {
            f32x4 vb = *(const f32x4*)(base + (size_t)sm.list[k + 16] * 8192);
            bx += vb.x; by += vb.y; bz += vb.z; bw_ += vb.w;
        }
    }
    ((f32x4*)sm.partials)[g * 32 + c] = (f32x4){ax, ay, az, aw};          // group g
    ((f32x4*)sm.partials)[(g + 16) * 32 + c] = (f32x4){bx, by, bz, bw_};  // group g+16
    __syncthreads();

    if (tid < 128) {
        float s = 0.f;
        #pragma unroll
        for (int gg = 0; gg < 32; ++gg) s += sm.partials[gg * 128 + tid];
        int j = mbase + tid;
        float v = m[j] + s;
        bool fire = (v >= THRESV);
        if (fire) v -= THRESV;
        m[j] = fire ? v : v * DECAYV;
        unsigned long long bm = __ballot(fire);
        if ((tid & 63) == 0) dst_words[tid >> 6] = bm;
    }
}

// ---- W2 partial: 128-col slice, 16 of 32 groups (half), 512B chunks,
// forced 8-deep; writes raw group partials to g_P (no LIF, no sync).
// Chain = ascending k ≡ gg (mod 32) — identical to all passing rounds.
__device__ __forceinline__ void gather_part128(const float* __restrict__ W, int colbase,
                                               int half, int count, SMem& sm,
                                               float* __restrict__ Pout) {
    int tid = threadIdx.x;
    int c = tid & 31;
    int gg = half * 16 + (tid >> 5);                 // group 0..31
    const float* base = W + (size_t)colbase + (size_t)c * 4;
    float ax = 0.f, ay = 0.f, az = 0.f, aw = 0.f;
    int k = gg;
    for (; k + 224 < count; k += 256) {              // forced 8-deep
        const float* p0 = base + (size_t)sm.list[k      ] * 8192;
        const float* p1 = base + (size_t)sm.list[k + 32 ] * 8192;
        const float* p2 = base + (size_t)sm.list[k + 64 ] * 8192;
        const float* p3 = base + (size_t)sm.list[k + 96 ] * 8192;
        const float* p4 = base + (size_t)sm.list[k + 128] * 8192;
        const float* p5 = base + (size_t)sm.list[k + 160] * 8192;
        const float* p6 = base + (size_t)sm.list[k + 192] * 8192;
        const float* p7 = base + (size_t)sm.list[k + 224] * 8192;
        f32x4 a0, a1, a2, a3, a4, a5, a6, a7;
        GLD(a0, p0); GLD(a1, p1); GLD(a2, p2); GLD(a3, p3);
        GLD(a4, p4); GLD(a5, p5); GLD(a6, p6); GLD(a7, p7);
        WAIT8(a0, a1, a2, a3, a4, a5, a6, a7);
        ax += a0.x; ay += a0.y; az += a0.z; aw += a0.w;
        ax += a1.x; ay += a1.y; az += a1.z; aw += a1.w;
        ax += a2.x; ay += a2.y; az += a2.z; aw += a2.w;
        ax += a3.x; ay += a3.y; az += a3.z; aw += a3.w;
        ax += a4.x; ay += a4.y; az += a4.z; aw += a4.w;
        ax += a5.x; ay += a5.y; az += a5.z; aw += a5.w;
        ax += a6.x; ay += a6.y; az += a6.z; aw += a6.w;
        ax += a7.x; ay += a7.y; az += a7.z; aw += a7.w;
    }
    for (; k + 96 < count; k += 128) {
        f32x4 v0 = *(const f32x4*)(base + (size_t)sm.list[k     ] * 8192);
        f32x4 v1 = *(const f32x4*)(base + (size_t)sm.list[k + 32] * 8192);
        f32x4 v2 = *(const f32x4*)(base + (size_t)sm.list[k + 64] * 8192);
        f32x4 v3 = *(const f32x4*)(base + (size_t)sm.list[k + 96] * 8192);
        ax += v0.x; ay += v0.y; az += v0.z; aw += v0.w;
        ax += v1.x; ay += v1.y; az += v1.z; aw += v1.w;
        ax += v2.x; ay += v2.y; az += v2.z; aw += v2.w;
        ax += v3.x; ay += v3.y; az += v3.z; aw += v3.w;
    }
    for (; k < count; k += 32) {
        f32x4 v = *(const f32x4*)(base + (size_t)sm.list[k] * 8192);
        ax += v.x; ay += v.y; az += v.z; aw += v.w;
    }
    *(f32x4*)(Pout + (size_t)gg * 128 + c * 4) = (f32x4){ax, ay, az, aw};
}

__global__ void __launch_bounds__(512)
snn_step_kernel(const float* __restrict__ W1, const float* __restrict__ W2,
                const float* __restrict__ W3,
                float* __restrict__ m1, float* __restrict__ m2, float* __restrict__ m3,
                const unsigned long long* __restrict__ sin_b,
                const unsigned long long* __restrict__ s1p_b,
                const unsigned long long* __restrict__ s2w3_b,
                unsigned long long* __restrict__ s1_out,
                unsigned long long* __restrict__ s2_out,
                float* __restrict__ out_row,
                int t, int nW1, int nW2, int nRed) {
    __shared__ SMem sm;
    int b = blockIdx.x;
    int tid = threadIdx.x;
    int par = t & 1;

    if (b < nW1) {
        // ---- W1 + LIF: s_in[t] -> s1[t] ----
        int count = compact_par<48>(sin_b, sm);
        gather_lif128(W1, b * 128, count, sm, m1, b * 128, &s1_out[2 * b]);
    } else if (b < nW1 + nW2) {
        // ---- W2 partials: s1[t-1] -> P[t] (parity par) ----
        int bb = b - nW1;
        int slice = bb >> 1, half = bb & 1;
        int count = compact_par<128>(s1p_b, sm);
        gather_part128(W2, slice * 128, half, count, sm, &g_P[par][slice][0][0]);
    } else if (b < nW1 + nW2 + nRed) {
        // ---- reduce P[t-1] (parity par^1) -> m2 LIF -> s2[t-1] ----
        int rb = b - nW1 - nW2;
        int j = rb * 512 + tid;                      // col 0..8191
        int slice = j >> 7, c = j & 127;
        const float* p = &g_P[par ^ 1][slice][0][c];
        float s = 0.f;
        #pragma unroll
        for (int gg = 0; gg < 32; ++gg) s += p[gg * 128];
        float v = m2[j] + s;
        bool fire = (v >= THRESV);
        if (fire) v -= THRESV;
        m2[j] = fire ? v : v * DECAYV;
        unsigned long long bm = __ballot(fire);
        if ((tid & 63) == 0) s2_out[j >> 6] = bm;
    } else {
        // ---- W3 (step t-1): s2[t-2] -> out[t] ----
        int count = compact_par<128>(s2w3_b, sm);
        int col = tid & 15, g = tid >> 4;            // g 0..31
        float acc = 0.f;
        if (col < 10) {
            for (int k = g; k < count; k += 32)
                acc += W3[(size_t)sm.list[k] * 10 + col];
        }
        sm.partials[g * 16 + col] = acc;
        __syncthreads();
        if (tid < 10) {
            float s = 0.f;
            for (int gg = 0; gg < 32; ++gg) s += sm.partials[gg * 16 + tid];
            float v = m3[tid] + s;
            bool fire = (v >= THRESV);
            if (fire) v -= THRESV;
            m3[tid] = fire ? v : v * DECAYV;
            out_row[tid] = fire ? 1.f : 0.f;
        }
    }
}

extern "C" void kernel_launch(void* const* d_in, const int* in_sizes, int n_in,
                              void* d_out, int out_size, void* d_ws, size_t ws_size,
                              hipStream_t stream) {
    const float* image = (const float*)d_in[0];
    const float* W1 = (const float*)d_in[1];
    const float* W2 = (const float*)d_in[2];
    const float* W3 = (const float*)d_in[3];
    float* out = (float*)d_out;

    char* ws = (char*)d_ws;
    float* m1 = (float*)ws;
    float* m2 = m1 + 8192;
    float* m3 = m2 + 8192;  // 16 floats
    unsigned long long* s_in_bits = (unsigned long long*)(ws + 65600);   // [20][48]
    unsigned long long* s1_bits = s_in_bits + TSTEPS * 48;               // [20][128]
    unsigned long long* s2_bits = s1_bits + TSTEPS * 128;                // [20][128]

    // zero membranes + output (harness poisons both; state must reset every launch)
    hipMemsetAsync(d_ws, 0, 65600, stream);
    hipMemsetAsync(d_out, 0, (size_t)out_size * sizeof(float), stream);

    snn_input_kernel<<<12, 256, 0, stream>>>(image, s_in_bits);

    // Pipeline: kernel t does W1(step t), W2-partials(step t), reduce(step t-1),
    // W3(step t-1). All deps cross kernel boundaries -> no intra-kernel sync.
    for (int t = 0; t <= 20; ++t) {
        int nW1 = (t <= 17) ? 64 : 0;    // s1[t] consumed at t+1 <= 18
        int nW2 = (t <= 18) ? 128 : 0;   // P[t] consumed at t+1 <= 19
        int nRed = (t >= 1 && t <= 19) ? 16 : 0;   // produces s2[t-1], 0..18
        int doW3 = (t >= 2) ? 1 : 0;     // out rows 2..20 (0,1 stay zero)
        int grid = nW1 + nW2 + nRed + doW3;
        if (grid == 0) continue;
        snn_step_kernel<<<grid, 512, 0, stream>>>(
            W1, W2, W3, m1, m2, m3,
            s_in_bits + (size_t)((t <= 17) ? t : 0) * 48,
            (t >= 1) ? s1_bits + (size_t)(t - 1) * 128 : nullptr,
            (t >= 2) ? s2_bits + (size_t)(t - 2) * 128 : nullptr,
            s1_bits + (size_t)((t <= 17) ? t : 0) * 128,
            (t >= 1) ? s2_bits + (size_t)(t - 1) * 128 : s2_bits,
            out + (size_t)t * 10,
            t, nW1, nW2, nRed);
    }
}

// Round 16
// 486.719 us; speedup vs baseline: 1.0331x; 1.0331x over previous
//
#include <hip/hip_runtime.h>

#define TSTEPS 20
#define THRESV 1.0f
#define DECAYV 0.9375f

typedef float f32x4 __attribute__((ext_vector_type(4)));

// Per-step gather sums (separated from the sequential LIF chains).
// Referenced ONLY from device code (host passes a selector int).
__device__ float g_sum1[TSTEPS][8192];   // 640 KB
__device__ float g_sum2[TSTEPS][8192];   // 640 KB ([0] unused)

// ws byte layout:
//   [0,      7680)   u64 s_in_bits[20][48]
//   [7680,  28160)   u64 s1_bits[20][128]
//   [28160, 48640)   u64 s2_bits[20][128]   (s2_bits[0] stays zero via memset)

__global__ void snn_input_kernel(const float* __restrict__ image,
                                 unsigned long long* __restrict__ s_in_bits) {
    int i = blockIdx.x * 256 + threadIdx.x;   // 0..3071
    float img = image[i];
    float mi = 0.f;
    int word = i >> 6, lane = i & 63;
    for (int t = 0; t < TSTEPS; ++t) {
        mi += img;
        bool fire = (mi >= THRESV);
        if (fire) mi -= THRESV;
        unsigned long long bm = __ballot(fire);
        if (lane == 0) s_in_bits[t * 48 + word] = bm;
    }
}

struct __align__(16) SMem {
    unsigned short list[8192];      // 16 KiB compacted firing-row indices
    float partials[4096];           // 16 KiB [32][128]
    unsigned long long bw[128];
    unsigned pc[128];
    int cntp;
    float m3s[16];                  // W3 kernel only
};

// Deterministic parallel compaction (ascending list order, bitwise-stable).
template <int NW>
__device__ __forceinline__ int compact_par(const unsigned long long* bits, SMem& sm) {
    int tid = threadIdx.x;
    if (tid < NW) {
        unsigned long long w = bits[tid];
        sm.bw[tid] = w;
        sm.pc[tid] = (unsigned)__popcll(w);
    }
    __syncthreads();
    constexpr int WPW = NW / 8;
    int wave = tid >> 6, lane = tid & 63;
    int w0 = wave * WPW;
    int base = 0;
    for (int i = lane; i < w0; i += 64) base += (int)sm.pc[i];
    #pragma unroll
    for (int off = 1; off < 64; off <<= 1) base += __shfl_xor(base, off);
    if (wave == 0) {
        int tot = 0;
        for (int i = lane; i < NW; i += 64) tot += (int)sm.pc[i];
        #pragma unroll
        for (int off = 1; off < 64; off <<= 1) tot += __shfl_xor(tot, off);
        if (lane == 0) sm.cntp = tot;
    }
    for (int i = 0; i < WPW; ++i) {
        unsigned long long w = sm.bw[w0 + i];
        if ((w >> lane) & 1ull) {
            int pos = base + __popcll(w & ((1ull << lane) - 1ull));
            sm.list[pos] = (unsigned short)(((w0 + i) << 6) + lane);
        }
        base += __popcll(w);
    }
    __syncthreads();
    return sm.cntp;
}

#define GLD(dst, ptr) \
    asm volatile("global_load_dwordx4 %0, %1, off" : "=v"(dst) : "v"(ptr))
#define WAIT8(a0,a1,a2,a3,a4,a5,a6,a7) \
    asm volatile("s_waitcnt vmcnt(0)" \
        : "+v"(a0),"+v"(a1),"+v"(a2),"+v"(a3),"+v"(a4),"+v"(a5),"+v"(a6),"+v"(a7))
#define WAIT4(a0,a1,a2,a3) \
    asm volatile("s_waitcnt vmcnt(0)" : "+v"(a0),"+v"(a1),"+v"(a2),"+v"(a3))

// 128-col slice gather, 512B chunks, dual chains (g, g+16), forced 8-deep.
// Per-(col,group) chain = ascending k (mod 32); reduce gg 0..31 ascending.
// => bitwise-identical sums to r12/r14. Writes 128 raw sums (no LIF).
__device__ __forceinline__ void gather_sum128(const float* __restrict__ W, int colbase,
                                              int count, SMem& sm,
                                              float* __restrict__ outp) {
    int tid = threadIdx.x;
    int c = tid & 31, g = tid >> 5;                  // c 0..31, g 0..15
    const float* base = W + (size_t)colbase + (size_t)c * 4;
    float ax = 0.f, ay = 0.f, az = 0.f, aw = 0.f;    // chain A (group g)
    float bx = 0.f, by = 0.f, bz = 0.f, bw_ = 0.f;   // chain B (group g+16)
    int k = g;
    for (; k + 112 < count; k += 128) {
        const float* pa0 = base + (size_t)sm.list[k      ] * 8192;
        const float* pa1 = base + (size_t)sm.list[k + 32 ] * 8192;
        const float* pa2 = base + (size_t)sm.list[k + 64 ] * 8192;
        const float* pa3 = base + (size_t)sm.list[k + 96 ] * 8192;
        const float* pb0 = base + (size_t)sm.list[k + 16 ] * 8192;
        const float* pb1 = base + (size_t)sm.list[k + 48 ] * 8192;
        const float* pb2 = base + (size_t)sm.list[k + 80 ] * 8192;
        const float* pb3 = base + (size_t)sm.list[k + 112] * 8192;
        f32x4 a0, a1, a2, a3, b0, b1, b2, b3;
        GLD(a0, pa0); GLD(b0, pb0); GLD(a1, pa1); GLD(b1, pb1);
        GLD(a2, pa2); GLD(b2, pb2); GLD(a3, pa3); GLD(b3, pb3);
        WAIT8(a0, b0, a1, b1, a2, b2, a3, b3);
        ax += a0.x; ay += a0.y; az += a0.z; aw += a0.w;
        ax += a1.x; ay += a1.y; az += a1.z; aw += a1.w;
        ax += a2.x; ay += a2.y; az += a2.z; aw += a2.w;
        ax += a3.x; ay += a3.y; az += a3.z; aw += a3.w;
        bx += b0.x; by += b0.y; bz += b0.z; bw_ += b0.w;
        bx += b1.x; by += b1.y; bz += b1.z; bw_ += b1.w;
        bx += b2.x; by += b2.y; bz += b2.z; bw_ += b2.w;
        bx += b3.x; by += b3.y; bz += b3.z; bw_ += b3.w;
    }
    for (; k + 48 < count; k += 64) {
        const float* pa0 = base + (size_t)sm.list[k     ] * 8192;
        const float* pa1 = base + (size_t)sm.list[k + 32] * 8192;
        const float* pb0 = base + (size_t)sm.list[k + 16] * 8192;
        const float* pb1 = base + (size_t)sm.list[k + 48] * 8192;
        f32x4 a0, a1, b0, b1;
        GLD(a0, pa0); GLD(b0, pb0); GLD(a1, pa1); GLD(b1, pb1);
        WAIT4(a0, b0, a1, b1);
        ax += a0.x; ay += a0.y; az += a0.z; aw += a0.w;
        ax += a1.x; ay += a1.y; az += a1.z; aw += a1.w;
        bx += b0.x; by += b0.y; bz += b0.z; bw_ += b0.w;
        bx += b1.x; by += b1.y; bz += b1.z; bw_ += b1.w;
    }
    for (; k < count; k += 32) {
        f32x4 va = *(const f32x4*)(base + (size_t)sm.list[k] * 8192);
        ax += va.x; ay += va.y; az += va.z; aw += va.w;
        if (k + 16 < count) {
            f32x4 vb = *(const f32x4*)(base + (size_t)sm.list[k + 16] * 8192);
            bx += vb.x; by += vb.y; bz += vb.z; bw_ += vb.w;
        }
    }
    ((f32x4*)sm.partials)[g * 32 + c] = (f32x4){ax, ay, az, aw};          // group g
    ((f32x4*)sm.partials)[(g + 16) * 32 + c] = (f32x4){bx, by, bz, bw_};  // group g+16
    __syncthreads();

    if (tid < 128) {
        float s = 0.f;
        #pragma unroll
        for (int gg = 0; gg < 32; ++gg) s += sm.partials[gg * 128 + tid];
        outp[tid] = s;
    }
}

// Kernel B: all 20 steps of W1 gathers. blockIdx -> (slice = b/20, t = b%20):
// same-slice blocks adjacent => cross-step L3/L2 reuse of W1 chunks.
__global__ void __launch_bounds__(512)
w1_sums_kernel(const float* __restrict__ W1,
               const unsigned long long* __restrict__ s_in_bits) {
    __shared__ SMem sm;
    int b = blockIdx.x;
    int slice = b / TSTEPS, t = b % TSTEPS;
    int count = compact_par<48>(s_in_bits + (size_t)t * 48, sm);
    gather_sum128(W1, slice * 128, count, sm, &g_sum1[t][slice * 128]);
}

// Kernel D: all 19 steps of W2 gathers. blockIdx -> (slice = b/19, t = 1+b%19).
__global__ void __launch_bounds__(512)
w2_sums_kernel(const float* __restrict__ W2,
               const unsigned long long* __restrict__ s1_bits) {
    __shared__ SMem sm;
    int b = blockIdx.x;
    int slice = b / (TSTEPS - 1), t = 1 + b % (TSTEPS - 1);
    int count = compact_par<128>(s1_bits + (size_t)(t - 1) * 128, sm);
    gather_sum128(W2, slice * 128, count, sm, &g_sum2[t][slice * 128]);
}

// Kernels C/E: sequential LIF chain per neuron (exact r12 arithmetic order).
// which=0 -> g_sum1, which=1 -> g_sum2 (device globals resolved in device code).
__global__ void __launch_bounds__(512)
lif_chain_kernel(int which,
                 unsigned long long* __restrict__ bits_out,  // [TSTEPS][128]
                 int tstart) {
    const float* sums = (which == 0) ? &g_sum1[0][0] : &g_sum2[0][0];
    int j = blockIdx.x * 512 + threadIdx.x;          // 0..8191
    int lane = threadIdx.x & 63;
    float m = 0.f;
    for (int t = tstart; t < TSTEPS; ++t) {
        float v = m + sums[(size_t)t * 8192 + j];
        bool fire = (v >= THRESV);
        if (fire) v -= THRESV;
        m = fire ? v : v * DECAYV;
        unsigned long long bm = __ballot(fire);
        if (lane == 0) bits_out[(size_t)t * 128 + (j >> 6)] = bm;
    }
}

// Kernel F: W3 + LIF3 over all steps, single block (tiny).
__global__ void __launch_bounds__(512)
w3_kernel(const float* __restrict__ W3,
          const unsigned long long* __restrict__ s2_bits,
          float* __restrict__ out) {
    __shared__ SMem sm;
    int tid = threadIdx.x;
    if (tid < 16) sm.m3s[tid] = 0.f;
    __syncthreads();
    for (int t = 1; t < TSTEPS; ++t) {
        int count = compact_par<128>(s2_bits + (size_t)(t - 1) * 128, sm);
        int col = tid & 15, g = tid >> 4;            // g 0..31
        float acc = 0.f;
        if (col < 10) {
            for (int k = g; k < count; k += 32)
                acc += W3[(size_t)sm.list[k] * 10 + col];
        }
        sm.partials[g * 16 + col] = acc;
        __syncthreads();
        if (tid < 10) {
            float s = 0.f;
            for (int gg = 0; gg < 32; ++gg) s += sm.partials[gg * 16 + tid];
            float v = sm.m3s[tid] + s;
            bool fire = (v >= THRESV);
            if (fire) v -= THRESV;
            sm.m3s[tid] = fire ? v : v * DECAYV;
            out[(t + 1) * 10 + tid] = fire ? 1.f : 0.f;
        }
        __syncthreads();
    }
}

extern "C" void kernel_launch(void* const* d_in, const int* in_sizes, int n_in,
                              void* d_out, int out_size, void* d_ws, size_t ws_size,
                              hipStream_t stream) {
    const float* image = (const float*)d_in[0];
    const float* W1 = (const float*)d_in[1];
    const float* W2 = (const float*)d_in[2];
    const float* W3 = (const float*)d_in[3];
    float* out = (float*)d_out;

    char* ws = (char*)d_ws;
    unsigned long long* s_in_bits = (unsigned long long*)ws;            // [20][48]
    unsigned long long* s1_bits = (unsigned long long*)(ws + 7680);     // [20][128]
    unsigned long long* s2_bits = (unsigned long long*)(ws + 28160);    // [20][128]

    // zero bit buffers (s2_bits[0] must be zero) + output
    hipMemsetAsync(d_ws, 0, 48640, stream);
    hipMemsetAsync(d_out, 0, (size_t)out_size * sizeof(float), stream);

    // A: input spikes for all steps
    snn_input_kernel<<<12, 256, 0, stream>>>(image, s_in_bits);
    // B: all W1 gather sums (W1-only working set -> L3-resident)
    w1_sums_kernel<<<64 * TSTEPS, 512, 0, stream>>>(W1, s_in_bits);
    // C: LIF chain layer 1 -> s1 bits
    lif_chain_kernel<<<16, 512, 0, stream>>>(0, s1_bits, 0);
    // D: all W2 gather sums (W2-only working set)
    w2_sums_kernel<<<64 * (TSTEPS - 1), 512, 0, stream>>>(W2, s1_bits);
    // E: LIF chain layer 2 -> s2 bits
    lif_chain_kernel<<<16, 512, 0, stream>>>(1, s2_bits, 1);
    // F: W3 + LIF3 -> output rows
    w3_kernel<<<1, 512, 0, stream>>>(W3, s2_bits, out);
}

// Round 17
// 309.632 us; speedup vs baseline: 1.6240x; 1.5719x over previous
//
#include <hip/hip_runtime.h>

#define TSTEPS 20
#define THRESV 1.0f
#define DECAYV 0.9375f

typedef float f32x4 __attribute__((ext_vector_type(4)));

// Per-step gather sums (separated from the sequential LIF chains).
// Referenced ONLY from device code (host passes a selector int).
__device__ float g_sum1[TSTEPS][8192];   // 640 KB
__device__ float g_sum2[TSTEPS][8192];   // 640 KB ([0] unused)
__device__ float g_sum3[TSTEPS][16];     // [0] unused

// ws byte layout:
//   [0,      7680)   u64 s_in_bits[20][48]
//   [7680,  28160)   u64 s1_bits[20][128]
//   [28160, 48640)   u64 s2_bits[20][128]   (s2_bits[0] stays zero via memset)

__global__ void snn_input_kernel(const float* __restrict__ image,
                                 unsigned long long* __restrict__ s_in_bits) {
    int i = blockIdx.x * 256 + threadIdx.x;   // 0..3071
    float img = image[i];
    float mi = 0.f;
    int word = i >> 6, lane = i & 63;
    for (int t = 0; t < TSTEPS; ++t) {
        mi += img;
        bool fire = (mi >= THRESV);
        if (fire) mi -= THRESV;
        unsigned long long bm = __ballot(fire);
        if (lane == 0) s_in_bits[t * 48 + word] = bm;
    }
}

struct __align__(16) SMem {
    unsigned short list[8192];      // 16 KiB compacted firing-row indices
    float partials[4096];           // 16 KiB [32][128]
    unsigned long long bw[128];
    unsigned pc[128];
    int cntp;
};

// Deterministic parallel compaction (ascending list order, bitwise-stable).
template <int NW>
__device__ __forceinline__ int compact_par(const unsigned long long* bits, SMem& sm) {
    int tid = threadIdx.x;
    if (tid < NW) {
        unsigned long long w = bits[tid];
        sm.bw[tid] = w;
        sm.pc[tid] = (unsigned)__popcll(w);
    }
    __syncthreads();
    constexpr int WPW = NW / 8;
    int wave = tid >> 6, lane = tid & 63;
    int w0 = wave * WPW;
    int base = 0;
    for (int i = lane; i < w0; i += 64) base += (int)sm.pc[i];
    #pragma unroll
    for (int off = 1; off < 64; off <<= 1) base += __shfl_xor(base, off);
    if (wave == 0) {
        int tot = 0;
        for (int i = lane; i < NW; i += 64) tot += (int)sm.pc[i];
        #pragma unroll
        for (int off = 1; off < 64; off <<= 1) tot += __shfl_xor(tot, off);
        if (lane == 0) sm.cntp = tot;
    }
    for (int i = 0; i < WPW; ++i) {
        unsigned long long w = sm.bw[w0 + i];
        if ((w >> lane) & 1ull) {
            int pos = base + __popcll(w & ((1ull << lane) - 1ull));
            sm.list[pos] = (unsigned short)(((w0 + i) << 6) + lane);
        }
        base += __popcll(w);
    }
    __syncthreads();
    return sm.cntp;
}

#define GLD(dst, ptr) \
    asm volatile("global_load_dwordx4 %0, %1, off" : "=v"(dst) : "v"(ptr))
#define WAIT8(a0,a1,a2,a3,a4,a5,a6,a7) \
    asm volatile("s_waitcnt vmcnt(0)" \
        : "+v"(a0),"+v"(a1),"+v"(a2),"+v"(a3),"+v"(a4),"+v"(a5),"+v"(a6),"+v"(a7))
#define WAIT4(a0,a1,a2,a3) \
    asm volatile("s_waitcnt vmcnt(0)" : "+v"(a0),"+v"(a1),"+v"(a2),"+v"(a3))

// 128-col slice gather, 512B chunks, dual chains (g, g+16), forced 8-deep.
// Per-(col,group) chain = ascending k (mod 32); reduce gg 0..31 ascending.
// => bitwise-identical sums to r12/r14/r16. Writes 128 raw sums (no LIF).
__device__ __forceinline__ void gather_sum128(const float* __restrict__ W, int colbase,
                                              int count, SMem& sm,
                                              float* __restrict__ outp) {
    int tid = threadIdx.x;
    int c = tid & 31, g = tid >> 5;                  // c 0..31, g 0..15
    const float* base = W + (size_t)colbase + (size_t)c * 4;
    float ax = 0.f, ay = 0.f, az = 0.f, aw = 0.f;    // chain A (group g)
    float bx = 0.f, by = 0.f, bz = 0.f, bw_ = 0.f;   // chain B (group g+16)
    int k = g;
    for (; k + 112 < count; k += 128) {
        const float* pa0 = base + (size_t)sm.list[k      ] * 8192;
        const float* pa1 = base + (size_t)sm.list[k + 32 ] * 8192;
        const float* pa2 = base + (size_t)sm.list[k + 64 ] * 8192;
        const float* pa3 = base + (size_t)sm.list[k + 96 ] * 8192;
        const float* pb0 = base + (size_t)sm.list[k + 16 ] * 8192;
        const float* pb1 = base + (size_t)sm.list[k + 48 ] * 8192;
        const float* pb2 = base + (size_t)sm.list[k + 80 ] * 8192;
        const float* pb3 = base + (size_t)sm.list[k + 112] * 8192;
        f32x4 a0, a1, a2, a3, b0, b1, b2, b3;
        GLD(a0, pa0); GLD(b0, pb0); GLD(a1, pa1); GLD(b1, pb1);
        GLD(a2, pa2); GLD(b2, pb2); GLD(a3, pa3); GLD(b3, pb3);
        WAIT8(a0, b0, a1, b1, a2, b2, a3, b3);
        ax += a0.x; ay += a0.y; az += a0.z; aw += a0.w;
        ax += a1.x; ay += a1.y; az += a1.z; aw += a1.w;
        ax += a2.x; ay += a2.y; az += a2.z; aw += a2.w;
        ax += a3.x; ay += a3.y; az += a3.z; aw += a3.w;
        bx += b0.x; by += b0.y; bz += b0.z; bw_ += b0.w;
        bx += b1.x; by += b1.y; bz += b1.z; bw_ += b1.w;
        bx += b2.x; by += b2.y; bz += b2.z; bw_ += b2.w;
        bx += b3.x; by += b3.y; bz += b3.z; bw_ += b3.w;
    }
    for (; k + 48 < count; k += 64) {
        const float* pa0 = base + (size_t)sm.list[k     ] * 8192;
        const float* pa1 = base + (size_t)sm.list[k + 32] * 8192;
        const float* pb0 = base + (size_t)sm.list[k + 16] * 8192;
        const float* pb1 = base + (size_t)sm.list[k + 48] * 8192;
        f32x4 a0, a1, b0, b1;
        GLD(a0, pa0); GLD(b0, pb0); GLD(a1, pa1); GLD(b1, pb1);
        WAIT4(a0, b0, a1, b1);
        ax += a0.x; ay += a0.y; az += a0.z; aw += a0.w;
        ax += a1.x; ay += a1.y; az += a1.z; aw += a1.w;
        bx += b0.x; by += b0.y; bz += b0.z; bw_ += b0.w;
        bx += b1.x; by += b1.y; bz += b1.z; bw_ += b1.w;
    }
    for (; k < count; k += 32) {
        f32x4 va = *(const f32x4*)(base + (size_t)sm.list[k] * 8192);
        ax += va.x; ay += va.y; az += va.z; aw += va.w;
        if (k + 16 < count) {
            f32x4 vb = *(const f32x4*)(base + (size_t)sm.list[k + 16] * 8192);
            bx += vb.x; by += vb.y; bz += vb.z; bw_ += vb.w;
        }
    }
    ((f32x4*)sm.partials)[g * 32 + c] = (f32x4){ax, ay, az, aw};          // group g
    ((f32x4*)sm.partials)[(g + 16) * 32 + c] = (f32x4){bx, by, bz, bw_};  // group g+16
    __syncthreads();

    if (tid < 128) {
        float s = 0.f;
        #pragma unroll
        for (int gg = 0; gg < 32; ++gg) s += sm.partials[gg * 128 + tid];
        outp[tid] = s;
    }
}

// Kernel B: all 20 steps of W1 gathers. blockIdx -> (slice = b/20, t = b%20):
// same-slice blocks adjacent => cross-step L3/L2 reuse of W1 chunks.
__global__ void __launch_bounds__(512)
w1_sums_kernel(const float* __restrict__ W1,
               const unsigned long long* __restrict__ s_in_bits) {
    __shared__ SMem sm;
    int b = blockIdx.x;
    int slice = b / TSTEPS, t = b % TSTEPS;
    int count = compact_par<48>(s_in_bits + (size_t)t * 48, sm);
    gather_sum128(W1, slice * 128, count, sm, &g_sum1[t][slice * 128]);
}

// Kernel D: all 19 steps of W2 gathers. blockIdx -> (slice = b/19, t = 1+b%19).
__global__ void __launch_bounds__(512)
w2_sums_kernel(const float* __restrict__ W2,
               const unsigned long long* __restrict__ s1_bits) {
    __shared__ SMem sm;
    int b = blockIdx.x;
    int slice = b / (TSTEPS - 1), t = 1 + b % (TSTEPS - 1);
    int count = compact_par<128>(s1_bits + (size_t)(t - 1) * 128, sm);
    gather_sum128(W2, slice * 128, count, sm, &g_sum2[t][slice * 128]);
}

// Kernels C/E: sequential LIF chain per neuron (exact r12 arithmetic order).
// which=0 -> g_sum1, which=1 -> g_sum2 (device globals resolved in device code).
__global__ void __launch_bounds__(512)
lif_chain_kernel(int which,
                 unsigned long long* __restrict__ bits_out,  // [TSTEPS][128]
                 int tstart) {
    const float* sums = (which == 0) ? &g_sum1[0][0] : &g_sum2[0][0];
    int j = blockIdx.x * 512 + threadIdx.x;          // 0..8191
    int lane = threadIdx.x & 63;
    float m = 0.f;
    for (int t = tstart; t < TSTEPS; ++t) {
        float v = m + sums[(size_t)t * 8192 + j];
        bool fire = (v >= THRESV);
        if (fire) v -= THRESV;
        m = fire ? v : v * DECAYV;
        unsigned long long bm = __ballot(fire);
        if (lane == 0) bits_out[(size_t)t * 128 + (j >> 6)] = bm;
    }
}

// Kernel F1: per-step W3 gather sums (19 parallel blocks, one per step).
// Exact same per-step chain as r16's w3_kernel body => bitwise-identical s.
__global__ void __launch_bounds__(512)
w3_sums_kernel(const float* __restrict__ W3,
               const unsigned long long* __restrict__ s2_bits) {
    __shared__ SMem sm;
    int t = blockIdx.x + 1;                          // 1..19
    int tid = threadIdx.x;
    int count = compact_par<128>(s2_bits + (size_t)(t - 1) * 128, sm);
    int col = tid & 15, g = tid >> 4;                // g 0..31
    float acc = 0.f;
    if (col < 10) {
        for (int k = g; k < count; k += 32)
            acc += W3[(size_t)sm.list[k] * 10 + col];
    }
    sm.partials[g * 16 + col] = acc;
    __syncthreads();
    if (tid < 10) {
        float s = 0.f;
        for (int gg = 0; gg < 32; ++gg) s += sm.partials[gg * 16 + tid];
        g_sum3[t][tid] = s;
    }
}

// Kernel F2: 10-neuron LIF chain over the 19 step sums (single wave).
__global__ void w3_lif_kernel(float* __restrict__ out) {
    int tid = threadIdx.x;
    if (tid < 10) {
        float m = 0.f;
        for (int t = 1; t < TSTEPS; ++t) {
            float v = m + g_sum3[t][tid];
            bool fire = (v >= THRESV);
            if (fire) v -= THRESV;
            m = fire ? v : v * DECAYV;
            out[(t + 1) * 10 + tid] = fire ? 1.f : 0.f;
        }
    }
}

extern "C" void kernel_launch(void* const* d_in, const int* in_sizes, int n_in,
                              void* d_out, int out_size, void* d_ws, size_t ws_size,
                              hipStream_t stream) {
    const float* image = (const float*)d_in[0];
    const float* W1 = (const float*)d_in[1];
    const float* W2 = (const float*)d_in[2];
    const float* W3 = (const float*)d_in[3];
    float* out = (float*)d_out;

    char* ws = (char*)d_ws;
    unsigned long long* s_in_bits = (unsigned long long*)ws;            // [20][48]
    unsigned long long* s1_bits = (unsigned long long*)(ws + 7680);     // [20][128]
    unsigned long long* s2_bits = (unsigned long long*)(ws + 28160);    // [20][128]

    // zero bit buffers (s2_bits[0] must be zero) + output (rows 0,1 stay zero)
    hipMemsetAsync(d_ws, 0, 48640, stream);
    hipMemsetAsync(d_out, 0, (size_t)out_size * sizeof(float), stream);

    // A: input spikes for all steps
    snn_input_kernel<<<12, 256, 0, stream>>>(image, s_in_bits);
    // B: all W1 gather sums (W1-only working set -> L3-resident)
    w1_sums_kernel<<<64 * TSTEPS, 512, 0, stream>>>(W1, s_in_bits);
    // C: LIF chain layer 1 -> s1 bits
    lif_chain_kernel<<<16, 512, 0, stream>>>(0, s1_bits, 0);
    // D: all W2 gather sums (W2-only working set)
    w2_sums_kernel<<<64 * (TSTEPS - 1), 512, 0, stream>>>(W2, s1_bits);
    // E: LIF chain layer 2 -> s2 bits
    lif_chain_kernel<<<16, 512, 0, stream>>>(1, s2_bits, 1);
    // F1: per-step W3 gather sums (parallel over steps)
    w3_sums_kernel<<<TSTEPS - 1, 512, 0, stream>>>(W3, s2_bits);
    // F2: 10-neuron LIF chain -> output rows
    w3_lif_kernel<<<1, 64, 0, stream>>>(out);
}

// Round 18
// 305.533 us; speedup vs baseline: 1.6458x; 1.0134x over previous
//
#include <hip/hip_runtime.h>

#define TSTEPS 20
#define THRESV 1.0f
#define DECAYV 0.9375f

typedef float f32x4 __attribute__((ext_vector_type(4)));

// Per-step gather sums (separated from the sequential LIF chains).
__device__ float g_sum1[TSTEPS][8192];   // 640 KB
__device__ float g_sum2[TSTEPS][8192];   // 640 KB ([0] unused)
__device__ float g_sum3[TSTEPS][16];     // [0] unused

// Precomputed per-step firing lists (ascending; built once, reused by all blocks).
__device__ unsigned short g_list1[TSTEPS][3072];
__device__ unsigned       g_cnt1[TSTEPS];
__device__ unsigned short g_list2[TSTEPS][8192];
__device__ unsigned       g_cnt2[TSTEPS];

// ws byte layout:
//   [0,      7680)   u64 s_in_bits[20][48]
//   [7680,  28160)   u64 s1_bits[20][128]
//   [28160, 48640)   u64 s2_bits[20][128]   (s2_bits[0] stays zero via memset)

__global__ void snn_input_kernel(const float* __restrict__ image,
                                 unsigned long long* __restrict__ s_in_bits) {
    int i = blockIdx.x * 256 + threadIdx.x;   // 0..3071
    float img = image[i];
    float mi = 0.f;
    int word = i >> 6, lane = i & 63;
    for (int t = 0; t < TSTEPS; ++t) {
        mi += img;
        bool fire = (mi >= THRESV);
        if (fire) mi -= THRESV;
        unsigned long long bm = __ballot(fire);
        if (lane == 0) s_in_bits[t * 48 + word] = bm;
    }
}

struct __align__(16) SMem {
    unsigned short list[8192];      // 16 KiB firing-row indices
    float partials[4096];           // 16 KiB [32][128]
    unsigned long long bw[128];
    unsigned pc[128];
    int cntp;
};

// Deterministic parallel compaction (ascending list order, bitwise-stable).
template <int NW>
__device__ __forceinline__ int compact_par(const unsigned long long* bits, SMem& sm) {
    int tid = threadIdx.x;
    if (tid < NW) {
        unsigned long long w = bits[tid];
        sm.bw[tid] = w;
        sm.pc[tid] = (unsigned)__popcll(w);
    }
    __syncthreads();
    constexpr int WPW = NW / 8;
    int wave = tid >> 6, lane = tid & 63;
    int w0 = wave * WPW;
    int base = 0;
    for (int i = lane; i < w0; i += 64) base += (int)sm.pc[i];
    #pragma unroll
    for (int off = 1; off < 64; off <<= 1) base += __shfl_xor(base, off);
    if (wave == 0) {
        int tot = 0;
        for (int i = lane; i < NW; i += 64) tot += (int)sm.pc[i];
        #pragma unroll
        for (int off = 1; off < 64; off <<= 1) tot += __shfl_xor(tot, off);
        if (lane == 0) sm.cntp = tot;
    }
    for (int i = 0; i < WPW; ++i) {
        unsigned long long w = sm.bw[w0 + i];
        if ((w >> lane) & 1ull) {
            int pos = base + __popcll(w & ((1ull << lane) - 1ull));
            sm.list[pos] = (unsigned short)(((w0 + i) << 6) + lane);
        }
        base += __popcll(w);
    }
    __syncthreads();
    return sm.cntp;
}

// Copy a precomputed list into LDS (cheap; replaces per-block compaction).
__device__ __forceinline__ int load_list(const unsigned short* __restrict__ gl,
                                         const unsigned* __restrict__ gcnt, SMem& sm) {
    int tid = threadIdx.x;
    int count = (int)*gcnt;
    for (int i = tid; i * 2 < count; i += 512)
        ((unsigned*)sm.list)[i] = ((const unsigned*)gl)[i];
    __syncthreads();
    return count;
}

// List-builder kernels (one block per step; list bytes identical to compact_par).
__global__ void __launch_bounds__(512)
build_lists1_kernel(const unsigned long long* __restrict__ s_in_bits) {
    __shared__ SMem sm;
    int t = blockIdx.x;                              // 0..19
    int tid = threadIdx.x;
    int count = compact_par<48>(s_in_bits + (size_t)t * 48, sm);
    for (int i = tid; i * 2 < count + 1; i += 512)
        ((unsigned*)&g_list1[t][0])[i] = ((unsigned*)sm.list)[i];
    if (tid == 0) g_cnt1[t] = (unsigned)count;
}

__global__ void __launch_bounds__(512)
build_lists2_kernel(const unsigned long long* __restrict__ s1_bits) {
    __shared__ SMem sm;
    int t = blockIdx.x + 1;                          // 1..19
    int tid = threadIdx.x;
    int count = compact_par<128>(s1_bits + (size_t)(t - 1) * 128, sm);
    for (int i = tid; i * 2 < count + 1; i += 512)
        ((unsigned*)&g_list2[t][0])[i] = ((unsigned*)sm.list)[i];
    if (tid == 0) g_cnt2[t] = (unsigned)count;
}

#define GLD(dst, ptr) \
    asm volatile("global_load_dwordx4 %0, %1, off" : "=v"(dst) : "v"(ptr))
#define WAIT8(a0,a1,a2,a3,a4,a5,a6,a7) \
    asm volatile("s_waitcnt vmcnt(0)" \
        : "+v"(a0),"+v"(a1),"+v"(a2),"+v"(a3),"+v"(a4),"+v"(a5),"+v"(a6),"+v"(a7))
#define WAIT4(a0,a1,a2,a3) \
    asm volatile("s_waitcnt vmcnt(0)" : "+v"(a0),"+v"(a1),"+v"(a2),"+v"(a3))

// 128-col slice gather, 512B chunks, dual chains (g, g+16), forced 8-deep.
// Per-(col,group) chain = ascending k (mod 32); reduce gg 0..31 ascending.
// => bitwise-identical sums to r12/r14/r16/r17. Writes 128 raw sums (no LIF).
__device__ __forceinline__ void gather_sum128(const float* __restrict__ W, int colbase,
                                              int count, SMem& sm,
                                              float* __restrict__ outp) {
    int tid = threadIdx.x;
    int c = tid & 31, g = tid >> 5;                  // c 0..31, g 0..15
    const float* base = W + (size_t)colbase + (size_t)c * 4;
    float ax = 0.f, ay = 0.f, az = 0.f, aw = 0.f;    // chain A (group g)
    float bx = 0.f, by = 0.f, bz = 0.f, bw_ = 0.f;   // chain B (group g+16)
    int k = g;
    for (; k + 112 < count; k += 128) {
        const float* pa0 = base + (size_t)sm.list[k      ] * 8192;
        const float* pa1 = base + (size_t)sm.list[k + 32 ] * 8192;
        const float* pa2 = base + (size_t)sm.list[k + 64 ] * 8192;
        const float* pa3 = base + (size_t)sm.list[k + 96 ] * 8192;
        const float* pb0 = base + (size_t)sm.list[k + 16 ] * 8192;
        const float* pb1 = base + (size_t)sm.list[k + 48 ] * 8192;
        const float* pb2 = base + (size_t)sm.list[k + 80 ] * 8192;
        const float* pb3 = base + (size_t)sm.list[k + 112] * 8192;
        f32x4 a0, a1, a2, a3, b0, b1, b2, b3;
        GLD(a0, pa0); GLD(b0, pb0); GLD(a1, pa1); GLD(b1, pb1);
        GLD(a2, pa2); GLD(b2, pb2); GLD(a3, pa3); GLD(b3, pb3);
        WAIT8(a0, b0, a1, b1, a2, b2, a3, b3);
        ax += a0.x; ay += a0.y; az += a0.z; aw += a0.w;
        ax += a1.x; ay += a1.y; az += a1.z; aw += a1.w;
        ax += a2.x; ay += a2.y; az += a2.z; aw += a2.w;
        ax += a3.x; ay += a3.y; az += a3.z; aw += a3.w;
        bx += b0.x; by += b0.y; bz += b0.z; bw_ += b0.w;
        bx += b1.x; by += b1.y; bz += b1.z; bw_ += b1.w;
        bx += b2.x; by += b2.y; bz += b2.z; bw_ += b2.w;
        bx += b3.x; by += b3.y; bz += b3.z; bw_ += b3.w;
    }
    for (; k + 48 < count; k += 64) {
        const float* pa0 = base + (size_t)sm.list[k     ] * 8192;
        const float* pa1 = base + (size_t)sm.list[k + 32] * 8192;
        const float* pb0 = base + (size_t)sm.list[k + 16] * 8192;
        const float* pb1 = base + (size_t)sm.list[k + 48] * 8192;
        f32x4 a0, a1, b0, b1;
        GLD(a0, pa0); GLD(b0, pb0); GLD(a1, pa1); GLD(b1, pb1);
        WAIT4(a0, b0, a1, b1);
        ax += a0.x; ay += a0.y; az += a0.z; aw += a0.w;
        ax += a1.x; ay += a1.y; az += a1.z; aw += a1.w;
        bx += b0.x; by += b0.y; bz += b0.z; bw_ += b0.w;
        bx += b1.x; by += b1.y; bz += b1.z; bw_ += b1.w;
    }
    for (; k < count; k += 32) {
        f32x4 va = *(const f32x4*)(base + (size_t)sm.list[k] * 8192);
        ax += va.x; ay += va.y; az += va.z; aw += va.w;
        if (k + 16 < count) {
            f32x4 vb = *(const f32x4*)(base + (size_t)sm.list[k + 16] * 8192);
            bx += vb.x; by += vb.y; bz += vb.z; bw_ += vb.w;
        }
    }
    ((f32x4*)sm.partials)[g * 32 + c] = (f32x4){ax, ay, az, aw};          // group g
    ((f32x4*)sm.partials)[(g + 16) * 32 + c] = (f32x4){bx, by, bz, bw_};  // group g+16
    __syncthreads();

    if (tid < 128) {
        float s = 0.f;
        #pragma unroll
        for (int gg = 0; gg < 32; ++gg) s += sm.partials[gg * 128 + tid];
        outp[tid] = s;
    }
}

// Kernel B: all 20 steps of W1 gathers (W1-only working set, 96 MB < L3).
__global__ void __launch_bounds__(512)
w1_sums_kernel(const float* __restrict__ W1) {
    __shared__ SMem sm;
    int b = blockIdx.x;
    int slice = b / TSTEPS, t = b % TSTEPS;
    int count = load_list(&g_list1[t][0], &g_cnt1[t], sm);
    gather_sum128(W1, slice * 128, count, sm, &g_sum1[t][slice * 128]);
}

// Kernel D: W2 gathers for a 32-slice COLUMN HALF (128 MB working set < L3,
// so cross-step reuse actually hits instead of thrashing).
__global__ void __launch_bounds__(512)
w2_sums_kernel(const float* __restrict__ W2, int slice0) {
    __shared__ SMem sm;
    int b = blockIdx.x;
    int slice = slice0 + b / (TSTEPS - 1), t = 1 + b % (TSTEPS - 1);
    int count = load_list(&g_list2[t][0], &g_cnt2[t], sm);
    gather_sum128(W2, slice * 128, count, sm, &g_sum2[t][slice * 128]);
}

// Kernels C/E: sequential LIF chain per neuron (exact r12 arithmetic order).
__global__ void __launch_bounds__(512)
lif_chain_kernel(int which,
                 unsigned long long* __restrict__ bits_out,  // [TSTEPS][128]
                 int tstart) {
    const float* sums = (which == 0) ? &g_sum1[0][0] : &g_sum2[0][0];
    int j = blockIdx.x * 512 + threadIdx.x;          // 0..8191
    int lane = threadIdx.x & 63;
    float m = 0.f;
    for (int t = tstart; t < TSTEPS; ++t) {
        float v = m + sums[(size_t)t * 8192 + j];
        bool fire = (v >= THRESV);
        if (fire) v -= THRESV;
        m = fire ? v : v * DECAYV;
        unsigned long long bm = __ballot(fire);
        if (lane == 0) bits_out[(size_t)t * 128 + (j >> 6)] = bm;
    }
}

// Kernel F1: per-step W3 gather sums (19 parallel blocks, one per step).
__global__ void __launch_bounds__(512)
w3_sums_kernel(const float* __restrict__ W3,
               const unsigned long long* __restrict__ s2_bits) {
    __shared__ SMem sm;
    int t = blockIdx.x + 1;                          // 1..19
    int tid = threadIdx.x;
    int count = compact_par<128>(s2_bits + (size_t)(t - 1) * 128, sm);
    int col = tid & 15, g = tid >> 4;                // g 0..31
    float acc = 0.f;
    if (col < 10) {
        for (int k = g; k < count; k += 32)
            acc += W3[(size_t)sm.list[k] * 10 + col];
    }
    sm.partials[g * 16 + col] = acc;
    __syncthreads();
    if (tid < 10) {
        float s = 0.f;
        for (int gg = 0; gg < 32; ++gg) s += sm.partials[gg * 16 + tid];
        g_sum3[t][tid] = s;
    }
}

// Kernel F2: 10-neuron LIF chain over the 19 step sums (single wave).
__global__ void w3_lif_kernel(float* __restrict__ out) {
    int tid = threadIdx.x;
    if (tid < 10) {
        float m = 0.f;
        for (int t = 1; t < TSTEPS; ++t) {
            float v = m + g_sum3[t][tid];
            bool fire = (v >= THRESV);
            if (fire) v -= THRESV;
            m = fire ? v : v * DECAYV;
            out[(t + 1) * 10 + tid] = fire ? 1.f : 0.f;
        }
    }
}

extern "C" void kernel_launch(void* const* d_in, const int* in_sizes, int n_in,
                              void* d_out, int out_size, void* d_ws, size_t ws_size,
                              hipStream_t stream) {
    const float* image = (const float*)d_in[0];
    const float* W1 = (const float*)d_in[1];
    const float* W2 = (const float*)d_in[2];
    const float* W3 = (const float*)d_in[3];
    float* out = (float*)d_out;

    char* ws = (char*)d_ws;
    unsigned long long* s_in_bits = (unsigned long long*)ws;            // [20][48]
    unsigned long long* s1_bits = (unsigned long long*)(ws + 7680);     // [20][128]
    unsigned long long* s2_bits = (unsigned long long*)(ws + 28160);    // [20][128]

    // zero bit buffers (s2_bits[0] must be zero) + output (rows 0,1 stay zero)
    hipMemsetAsync(d_ws, 0, 48640, stream);
    hipMemsetAsync(d_out, 0, (size_t)out_size * sizeof(float), stream);

    // A: input spikes for all steps
    snn_input_kernel<<<12, 256, 0, stream>>>(image, s_in_bits);
    // L1: firing lists for input spikes (once per step)
    build_lists1_kernel<<<TSTEPS, 512, 0, stream>>>(s_in_bits);
    // B: all W1 gather sums
    w1_sums_kernel<<<64 * TSTEPS, 512, 0, stream>>>(W1);
    // C: LIF chain layer 1 -> s1 bits
    lif_chain_kernel<<<16, 512, 0, stream>>>(0, s1_bits, 0);
    // L2: firing lists for layer-1 spikes
    build_lists2_kernel<<<TSTEPS - 1, 512, 0, stream>>>(s1_bits);
    // D: W2 gather sums in two column-half passes (128 MB L3-resident each)
    w2_sums_kernel<<<32 * (TSTEPS - 1), 512, 0, stream>>>(W2, 0);
    w2_sums_kernel<<<32 * (TSTEPS - 1), 512, 0, stream>>>(W2, 32);
    // E: LIF chain layer 2 -> s2 bits
    lif_chain_kernel<<<16, 512, 0, stream>>>(1, s2_bits, 1);
    // F1: per-step W3 gather sums (parallel over steps)
    w3_sums_kernel<<<TSTEPS - 1, 512, 0, stream>>>(W3, s2_bits);
    // F2: 10-neuron LIF chain -> output rows
    w3_lif_kernel<<<1, 64, 0, stream>>>(out);
}

// Round 19
// 303.539 us; speedup vs baseline: 1.6566x; 1.0066x over previous
//
#include <hip/hip_runtime.h>

#define TSTEPS 20
#define THRESV 1.0f
#define DECAYV 0.9375f

typedef float f32x4 __attribute__((ext_vector_type(4)));

// Per-step gather sums (separated from the sequential LIF chains).
__device__ float g_sum1[TSTEPS][8192];   // 640 KB
__device__ float g_sum2[TSTEPS][8192];   // 640 KB ([0] unused)
__device__ float g_sum3[TSTEPS][16];     // [0] unused

// Precomputed per-step firing lists (ascending; built once, reused by all blocks).
__device__ unsigned short g_list1[TSTEPS][3072];
__device__ unsigned       g_cnt1[TSTEPS];
__device__ unsigned short g_list2[TSTEPS][8192];
__device__ unsigned       g_cnt2[TSTEPS];

// ws byte layout:
//   [0,      7680)   u64 s_in_bits[20][48]
//   [7680,  28160)   u64 s1_bits[20][128]
//   [28160, 48640)   u64 s2_bits[20][128]   (s2_bits[0] stays zero via memset)

__global__ void snn_input_kernel(const float* __restrict__ image,
                                 unsigned long long* __restrict__ s_in_bits) {
    int i = blockIdx.x * 256 + threadIdx.x;   // 0..3071
    float img = image[i];
    float mi = 0.f;
    int word = i >> 6, lane = i & 63;
    for (int t = 0; t < TSTEPS; ++t) {
        mi += img;
        bool fire = (mi >= THRESV);
        if (fire) mi -= THRESV;
        unsigned long long bm = __ballot(fire);
        if (lane == 0) s_in_bits[t * 48 + word] = bm;
    }
}

struct __align__(16) SMem {
    unsigned short list[8192];      // 16 KiB firing-row indices
    float partials[8192];           // 32 KiB [32 groups][256 cols]
    unsigned long long bw[128];
    unsigned pc[128];
    int cntp;
};

// Deterministic parallel compaction (ascending list order, bitwise-stable).
template <int NW>
__device__ __forceinline__ int compact_par(const unsigned long long* bits, SMem& sm) {
    int tid = threadIdx.x;
    if (tid < NW) {
        unsigned long long w = bits[tid];
        sm.bw[tid] = w;
        sm.pc[tid] = (unsigned)__popcll(w);
    }
    __syncthreads();
    constexpr int WPW = NW / 8;
    int wave = tid >> 6, lane = tid & 63;
    int w0 = wave * WPW;
    int base = 0;
    for (int i = lane; i < w0; i += 64) base += (int)sm.pc[i];
    #pragma unroll
    for (int off = 1; off < 64; off <<= 1) base += __shfl_xor(base, off);
    if (wave == 0) {
        int tot = 0;
        for (int i = lane; i < NW; i += 64) tot += (int)sm.pc[i];
        #pragma unroll
        for (int off = 1; off < 64; off <<= 1) tot += __shfl_xor(tot, off);
        if (lane == 0) sm.cntp = tot;
    }
    for (int i = 0; i < WPW; ++i) {
        unsigned long long w = sm.bw[w0 + i];
        if ((w >> lane) & 1ull) {
            int pos = base + __popcll(w & ((1ull << lane) - 1ull));
            sm.list[pos] = (unsigned short)(((w0 + i) << 6) + lane);
        }
        base += __popcll(w);
    }
    __syncthreads();
    return sm.cntp;
}

// Copy a precomputed list into LDS (replaces per-block compaction).
__device__ __forceinline__ int load_list(const unsigned short* __restrict__ gl,
                                         const unsigned* __restrict__ gcnt, SMem& sm) {
    int tid = threadIdx.x;
    int count = (int)*gcnt;
    int nw = (count + 1) >> 1;                       // u32 words
    for (int i = tid; i < nw; i += 512)
        ((unsigned*)sm.list)[i] = ((const unsigned*)gl)[i];
    __syncthreads();
    return count;
}

// List-builder kernels (one block per step; list bytes identical to compact_par).
__global__ void __launch_bounds__(512)
build_lists1_kernel(const unsigned long long* __restrict__ s_in_bits) {
    __shared__ SMem sm;
    int t = blockIdx.x;                              // 0..19
    int tid = threadIdx.x;
    int count = compact_par<48>(s_in_bits + (size_t)t * 48, sm);
    int nw = (count + 1) >> 1;
    for (int i = tid; i < nw; i += 512)
        ((unsigned*)&g_list1[t][0])[i] = ((unsigned*)sm.list)[i];
    if (tid == 0) g_cnt1[t] = (unsigned)count;
}

__global__ void __launch_bounds__(512)
build_lists2_kernel(const unsigned long long* __restrict__ s1_bits) {
    __shared__ SMem sm;
    int t = blockIdx.x + 1;                          // 1..19
    int tid = threadIdx.x;
    int count = compact_par<128>(s1_bits + (size_t)(t - 1) * 128, sm);
    int nw = (count + 1) >> 1;
    for (int i = tid; i < nw; i += 512)
        ((unsigned*)&g_list2[t][0])[i] = ((unsigned*)sm.list)[i];
    if (tid == 0) g_cnt2[t] = (unsigned)count;
}

#define GLD(dst, ptr) \
    asm volatile("global_load_dwordx4 %0, %1, off" : "=v"(dst) : "v"(ptr))
#define WAIT8(a0,a1,a2,a3,a4,a5,a6,a7) \
    asm volatile("s_waitcnt vmcnt(0)" \
        : "+v"(a0),"+v"(a1),"+v"(a2),"+v"(a3),"+v"(a4),"+v"(a5),"+v"(a6),"+v"(a7))

// 256-col slice gather, 1 KB contiguous per row (64 lanes x 16B), 4 chains
// per thread (groups gq, gq+8, gq+16, gq+24), 8 asm-forced loads in flight.
// Per-(col,group) chain = ascending k (mod 32); per-col reduce gg 0..31
// ascending => bitwise-identical g_sum values to r17/r18.
__device__ __forceinline__ void gather_sum256(const float* __restrict__ W, int colbase,
                                              int count, SMem& sm,
                                              float* __restrict__ outp) {
    int tid = threadIdx.x;
    int c = tid & 63, gq = tid >> 6;                 // c: 16B chunk 0..63, gq: 0..7
    const float* base = W + (size_t)colbase + (size_t)c * 4;
    f32x4 s0 = {0.f, 0.f, 0.f, 0.f};                 // chain gq
    f32x4 s1 = {0.f, 0.f, 0.f, 0.f};                 // chain gq+8
    f32x4 s2 = {0.f, 0.f, 0.f, 0.f};                 // chain gq+16
    f32x4 s3 = {0.f, 0.f, 0.f, 0.f};                 // chain gq+24
    int k = gq;
    for (; k + 56 < count; k += 64) {                // 2 steps per chain, 8 in flight
        const float* p00 = base + (size_t)sm.list[k     ] * 8192;
        const float* p01 = base + (size_t)sm.list[k + 32] * 8192;
        const float* p10 = base + (size_t)sm.list[k + 8 ] * 8192;
        const float* p11 = base + (size_t)sm.list[k + 40] * 8192;
        const float* p20 = base + (size_t)sm.list[k + 16] * 8192;
        const float* p21 = base + (size_t)sm.list[k + 48] * 8192;
        const float* p30 = base + (size_t)sm.list[k + 24] * 8192;
        const float* p31 = base + (size_t)sm.list[k + 56] * 8192;
        f32x4 a00, a01, a10, a11, a20, a21, a30, a31;
        GLD(a00, p00); GLD(a10, p10); GLD(a20, p20); GLD(a30, p30);
        GLD(a01, p01); GLD(a11, p11); GLD(a21, p21); GLD(a31, p31);
        WAIT8(a00, a10, a20, a30, a01, a11, a21, a31);
        s0 += a00; s0 += a01;                        // ascending within chain
        s1 += a10; s1 += a11;
        s2 += a20; s2 += a21;
        s3 += a30; s3 += a31;
    }
    for (int kj = k; kj < count; kj += 32)           // chain gq tail
        s0 += *(const f32x4*)(base + (size_t)sm.list[kj] * 8192);
    for (int kj = k + 8; kj < count; kj += 32)       // chain gq+8 tail
        s1 += *(const f32x4*)(base + (size_t)sm.list[kj] * 8192);
    for (int kj = k + 16; kj < count; kj += 32)      // chain gq+16 tail
        s2 += *(const f32x4*)(base + (size_t)sm.list[kj] * 8192);
    for (int kj = k + 24; kj < count; kj += 32)      // chain gq+24 tail
        s3 += *(const f32x4*)(base + (size_t)sm.list[kj] * 8192);

    ((f32x4*)sm.partials)[(gq     ) * 64 + c] = s0;  // [group][256 cols]
    ((f32x4*)sm.partials)[(gq + 8 ) * 64 + c] = s1;
    ((f32x4*)sm.partials)[(gq + 16) * 64 + c] = s2;
    ((f32x4*)sm.partials)[(gq + 24) * 64 + c] = s3;
    __syncthreads();

    if (tid < 256) {
        float s = 0.f;
        #pragma unroll
        for (int gg = 0; gg < 32; ++gg) s += sm.partials[gg * 256 + tid];
        outp[tid] = s;
    }
}

// Kernel B: all 20 steps of W1 gathers (32 slices x 20 t = 640 blocks).
__global__ void __launch_bounds__(512)
w1_sums_kernel(const float* __restrict__ W1) {
    __shared__ SMem sm;
    int b = blockIdx.x;
    int slice = b / TSTEPS, t = b % TSTEPS;
    int count = load_list(&g_list1[t][0], &g_cnt1[t], sm);
    gather_sum256(W1, slice * 256, count, sm, &g_sum1[t][slice * 256]);
}

// Kernel D: all 19 steps of W2 gathers (32 slices x 19 t = 608 blocks).
__global__ void __launch_bounds__(512)
w2_sums_kernel(const float* __restrict__ W2) {
    __shared__ SMem sm;
    int b = blockIdx.x;
    int slice = b / (TSTEPS - 1), t = 1 + b % (TSTEPS - 1);
    int count = load_list(&g_list2[t][0], &g_cnt2[t], sm);
    gather_sum256(W2, slice * 256, count, sm, &g_sum2[t][slice * 256]);
}

// Kernels C/E: sequential LIF chain per neuron (exact r12 arithmetic order).
__global__ void __launch_bounds__(512)
lif_chain_kernel(int which,
                 unsigned long long* __restrict__ bits_out,  // [TSTEPS][128]
                 int tstart) {
    const float* sums = (which == 0) ? &g_sum1[0][0] : &g_sum2[0][0];
    int j = blockIdx.x * 512 + threadIdx.x;          // 0..8191
    int lane = threadIdx.x & 63;
    float m = 0.f;
    for (int t = tstart; t < TSTEPS; ++t) {
        float v = m + sums[(size_t)t * 8192 + j];
        bool fire = (v >= THRESV);
        if (fire) v -= THRESV;
        m = fire ? v : v * DECAYV;
        unsigned long long bm = __ballot(fire);
        if (lane == 0) bits_out[(size_t)t * 128 + (j >> 6)] = bm;
    }
}

// Kernel F1: per-step W3 gather sums (19 parallel blocks, one per step).
__global__ void __launch_bounds__(512)
w3_sums_kernel(const float* __restrict__ W3,
               const unsigned long long* __restrict__ s2_bits) {
    __shared__ SMem sm;
    int t = blockIdx.x + 1;                          // 1..19
    int tid = threadIdx.x;
    int count = compact_par<128>(s2_bits + (size_t)(t - 1) * 128, sm);
    int col = tid & 15, g = tid >> 4;                // g 0..31
    float acc = 0.f;
    if (col < 10) {
        for (int k = g; k < count; k += 32)
            acc += W3[(size_t)sm.list[k] * 10 + col];
    }
    sm.partials[g * 16 + col] = acc;
    __syncthreads();
    if (tid < 10) {
        float s = 0.f;
        for (int gg = 0; gg < 32; ++gg) s += sm.partials[gg * 16 + tid];
        g_sum3[t][tid] = s;
    }
}

// Kernel F2: 10-neuron LIF chain over the 19 step sums (single wave).
__global__ void w3_lif_kernel(float* __restrict__ out) {
    int tid = threadIdx.x;
    if (tid < 10) {
        float m = 0.f;
        for (int t = 1; t < TSTEPS; ++t) {
            float v = m + g_sum3[t][tid];
            bool fire = (v >= THRESV);
            if (fire) v -= THRESV;
            m = fire ? v : v * DECAYV;
            out[(t + 1) * 10 + tid] = fire ? 1.f : 0.f;
        }
    }
}

extern "C" void kernel_launch(void* const* d_in, const int* in_sizes, int n_in,
                              void* d_out, int out_size, void* d_ws, size_t ws_size,
                              hipStream_t stream) {
    const float* image = (const float*)d_in[0];
    const float* W1 = (const float*)d_in[1];
    const float* W2 = (const float*)d_in[2];
    const float* W3 = (const float*)d_in[3];
    float* out = (float*)d_out;

    char* ws = (char*)d_ws;
    unsigned long long* s_in_bits = (unsigned long long*)ws;            // [20][48]
    unsigned long long* s1_bits = (unsigned long long*)(ws + 7680);     // [20][128]
    unsigned long long* s2_bits = (unsigned long long*)(ws + 28160);    // [20][128]

    // zero bit buffers (s2_bits[0] must be zero) + output (rows 0,1 stay zero)
    hipMemsetAsync(d_ws, 0, 48640, stream);
    hipMemsetAsync(d_out, 0, (size_t)out_size * sizeof(float), stream);

    // A: input spikes for all steps
    snn_input_kernel<<<12, 256, 0, stream>>>(image, s_in_bits);
    // L1: firing lists for input spikes (once per step)
    build_lists1_kernel<<<TSTEPS, 512, 0, stream>>>(s_in_bits);
    // B: all W1 gather sums (1 KB row chunks)
    w1_sums_kernel<<<32 * TSTEPS, 512, 0, stream>>>(W1);
    // C: LIF chain layer 1 -> s1 bits
    lif_chain_kernel<<<16, 512, 0, stream>>>(0, s1_bits, 0);
    // L2: firing lists for layer-1 spikes
    build_lists2_kernel<<<TSTEPS - 1, 512, 0, stream>>>(s1_bits);
    // D: all W2 gather sums (1 KB row chunks)
    w2_sums_kernel<<<32 * (TSTEPS - 1), 512, 0, stream>>>(W2);
    // E: LIF chain layer 2 -> s2 bits
    lif_chain_kernel<<<16, 512, 0, stream>>>(1, s2_bits, 1);
    // F1: per-step W3 gather sums (parallel over steps)
    w3_sums_kernel<<<TSTEPS - 1, 512, 0, stream>>>(W3, s2_bits);
    // F2: 10-neuron LIF chain -> output rows
    w3_lif_kernel<<<1, 64, 0, stream>>>(out);
}

// Round 20
// 236.631 us; speedup vs baseline: 2.1250x; 1.2828x over previous
//
#include <hip/hip_runtime.h>

#define TSTEPS 20
#define THRESV 1.0f
#define DECAYV 0.9375f

typedef float f32x4 __attribute__((ext_vector_type(4)));
typedef float f32x2 __attribute__((ext_vector_type(2)));

// Per-step gather sums (separated from the sequential LIF chains).
__device__ float g_sum1[TSTEPS][8192];   // 640 KB
__device__ float g_sum2[TSTEPS][8192];   // 640 KB ([0] unused)
__device__ float g_sum3[TSTEPS][16];     // [0] unused

// Precomputed per-step firing lists for W1 (sparse path, unchanged).
__device__ unsigned short g_list1[TSTEPS][3072];
__device__ unsigned       g_cnt1[TSTEPS];

// Dense W2 path: per-row 19-bit fire masks + row-block partials.
__device__ unsigned g_mask2[8192];
__device__ float g_part2[64][19][8192];  // 40 MB

// ws byte layout:
//   [0,      7680)   u64 s_in_bits[20][48]
//   [7680,  28160)   u64 s1_bits[20][128]
//   [28160, 48640)   u64 s2_bits[20][128]   (s2_bits[0] stays zero via memset)

__global__ void snn_input_kernel(const float* __restrict__ image,
                                 unsigned long long* __restrict__ s_in_bits) {
    int i = blockIdx.x * 256 + threadIdx.x;   // 0..3071
    float img = image[i];
    float mi = 0.f;
    int word = i >> 6, lane = i & 63;
    for (int t = 0; t < TSTEPS; ++t) {
        mi += img;
        bool fire = (mi >= THRESV);
        if (fire) mi -= THRESV;
        unsigned long long bm = __ballot(fire);
        if (lane == 0) s_in_bits[t * 48 + word] = bm;
    }
}

struct __align__(16) SMem {
    unsigned short list[8192];      // 16 KiB firing-row indices
    float partials[8192];           // 32 KiB [32 groups][256 cols]
    unsigned long long bw[128];
    unsigned pc[128];
    int cntp;
};

// Deterministic parallel compaction (ascending list order, bitwise-stable).
template <int NW>
__device__ __forceinline__ int compact_par(const unsigned long long* bits, SMem& sm) {
    int tid = threadIdx.x;
    if (tid < NW) {
        unsigned long long w = bits[tid];
        sm.bw[tid] = w;
        sm.pc[tid] = (unsigned)__popcll(w);
    }
    __syncthreads();
    constexpr int WPW = NW / 8;
    int wave = tid >> 6, lane = tid & 63;
    int w0 = wave * WPW;
    int base = 0;
    for (int i = lane; i < w0; i += 64) base += (int)sm.pc[i];
    #pragma unroll
    for (int off = 1; off < 64; off <<= 1) base += __shfl_xor(base, off);
    if (wave == 0) {
        int tot = 0;
        for (int i = lane; i < NW; i += 64) tot += (int)sm.pc[i];
        #pragma unroll
        for (int off = 1; off < 64; off <<= 1) tot += __shfl_xor(tot, off);
        if (lane == 0) sm.cntp = tot;
    }
    for (int i = 0; i < WPW; ++i) {
        unsigned long long w = sm.bw[w0 + i];
        if ((w >> lane) & 1ull) {
            int pos = base + __popcll(w & ((1ull << lane) - 1ull));
            sm.list[pos] = (unsigned short)(((w0 + i) << 6) + lane);
        }
        base += __popcll(w);
    }
    __syncthreads();
    return sm.cntp;
}

// Copy a precomputed list into LDS (replaces per-block compaction).
__device__ __forceinline__ int load_list(const unsigned short* __restrict__ gl,
                                         const unsigned* __restrict__ gcnt, SMem& sm) {
    int tid = threadIdx.x;
    int count = (int)*gcnt;
    int nw = (count + 1) >> 1;                       // u32 words
    for (int i = tid; i < nw; i += 512)
        ((unsigned*)sm.list)[i] = ((const unsigned*)gl)[i];
    __syncthreads();
    return count;
}

__global__ void __launch_bounds__(512)
build_lists1_kernel(const unsigned long long* __restrict__ s_in_bits) {
    __shared__ SMem sm;
    int t = blockIdx.x;                              // 0..19
    int tid = threadIdx.x;
    int count = compact_par<48>(s_in_bits + (size_t)t * 48, sm);
    int nw = (count + 1) >> 1;
    for (int i = tid; i < nw; i += 512)
        ((unsigned*)&g_list1[t][0])[i] = ((unsigned*)sm.list)[i];
    if (tid == 0) g_cnt1[t] = (unsigned)count;
}

#define GLD(dst, ptr) \
    asm volatile("global_load_dwordx4 %0, %1, off" : "=v"(dst) : "v"(ptr))
#define GLD2(dst, ptr) \
    asm volatile("global_load_dwordx2 %0, %1, off" : "=v"(dst) : "v"(ptr))
#define WAIT8(a0,a1,a2,a3,a4,a5,a6,a7) \
    asm volatile("s_waitcnt vmcnt(0)" \
        : "+v"(a0),"+v"(a1),"+v"(a2),"+v"(a3),"+v"(a4),"+v"(a5),"+v"(a6),"+v"(a7))

// 256-col slice sparse gather (W1 path, unchanged from r19 — bitwise-stable).
__device__ __forceinline__ void gather_sum256(const float* __restrict__ W, int colbase,
                                              int count, SMem& sm,
                                              float* __restrict__ outp) {
    int tid = threadIdx.x;
    int c = tid & 63, gq = tid >> 6;                 // c: 16B chunk 0..63, gq: 0..7
    const float* base = W + (size_t)colbase + (size_t)c * 4;
    f32x4 s0 = {0.f, 0.f, 0.f, 0.f};
    f32x4 s1 = {0.f, 0.f, 0.f, 0.f};
    f32x4 s2 = {0.f, 0.f, 0.f, 0.f};
    f32x4 s3 = {0.f, 0.f, 0.f, 0.f};
    int k = gq;
    for (; k + 56 < count; k += 64) {
        const float* p00 = base + (size_t)sm.list[k     ] * 8192;
        const float* p01 = base + (size_t)sm.list[k + 32] * 8192;
        const float* p10 = base + (size_t)sm.list[k + 8 ] * 8192;
        const float* p11 = base + (size_t)sm.list[k + 40] * 8192;
        const float* p20 = base + (size_t)sm.list[k + 16] * 8192;
        const float* p21 = base + (size_t)sm.list[k + 48] * 8192;
        const float* p30 = base + (size_t)sm.list[k + 24] * 8192;
        const float* p31 = base + (size_t)sm.list[k + 56] * 8192;
        f32x4 a00, a01, a10, a11, a20, a21, a30, a31;
        GLD(a00, p00); GLD(a10, p10); GLD(a20, p20); GLD(a30, p30);
        GLD(a01, p01); GLD(a11, p11); GLD(a21, p21); GLD(a31, p31);
        WAIT8(a00, a10, a20, a30, a01, a11, a21, a31);
        s0 += a00; s0 += a01;
        s1 += a10; s1 += a11;
        s2 += a20; s2 += a21;
        s3 += a30; s3 += a31;
    }
    for (int kj = k; kj < count; kj += 32)
        s0 += *(const f32x4*)(base + (size_t)sm.list[kj] * 8192);
    for (int kj = k + 8; kj < count; kj += 32)
        s1 += *(const f32x4*)(base + (size_t)sm.list[kj] * 8192);
    for (int kj = k + 16; kj < count; kj += 32)
        s2 += *(const f32x4*)(base + (size_t)sm.list[kj] * 8192);
    for (int kj = k + 24; kj < count; kj += 32)
        s3 += *(const f32x4*)(base + (size_t)sm.list[kj] * 8192);

    ((f32x4*)sm.partials)[(gq     ) * 64 + c] = s0;
    ((f32x4*)sm.partials)[(gq + 8 ) * 64 + c] = s1;
    ((f32x4*)sm.partials)[(gq + 16) * 64 + c] = s2;
    ((f32x4*)sm.partials)[(gq + 24) * 64 + c] = s3;
    __syncthreads();

    if (tid < 256) {
        float s = 0.f;
        #pragma unroll
        for (int gg = 0; gg < 32; ++gg) s += sm.partials[gg * 256 + tid];
        outp[tid] = s;
    }
}

// Kernel B: all 20 steps of W1 gathers (32 slices x 20 t = 640 blocks).
__global__ void __launch_bounds__(512)
w1_sums_kernel(const float* __restrict__ W1) {
    __shared__ SMem sm;
    int b = blockIdx.x;
    int slice = b / TSTEPS, t = b % TSTEPS;
    int count = load_list(&g_list1[t][0], &g_cnt1[t], sm);
    gather_sum256(W1, slice * 256, count, sm, &g_sum1[t][slice * 256]);
}

// Kernels C/E: sequential LIF chain per neuron.
__global__ void __launch_bounds__(512)
lif_chain_kernel(int which,
                 unsigned long long* __restrict__ bits_out,  // [TSTEPS][128]
                 int tstart) {
    const float* sums = (which == 0) ? &g_sum1[0][0] : &g_sum2[0][0];
    int j = blockIdx.x * 512 + threadIdx.x;          // 0..8191
    int lane = threadIdx.x & 63;
    float m = 0.f;
    for (int t = tstart; t < TSTEPS; ++t) {
        float v = m + sums[(size_t)t * 8192 + j];
        bool fire = (v >= THRESV);
        if (fire) v -= THRESV;
        m = fire ? v : v * DECAYV;
        unsigned long long bm = __ballot(fire);
        if (lane == 0) bits_out[(size_t)t * 128 + (j >> 6)] = bm;
    }
}

// ---- Dense W2 path ----
// M2: per-row 19-bit masks (bit b = fired at step b, feeding sum2[b+1]).
__global__ void __launch_bounds__(512)
build_mask2_kernel(const unsigned long long* __restrict__ s1_bits) {
    int i = blockIdx.x * 512 + threadIdx.x;          // 0..8191
    unsigned m = 0;
    #pragma unroll
    for (int b = 0; b < 19; ++b)
        m |= (unsigned)((s1_bits[(size_t)b * 128 + (i >> 6)] >> (i & 63)) & 1ull) << b;
    g_mask2[i] = m;
}

__device__ __forceinline__ void accrow(f32x2 w, unsigned m, float* ax, float* ay) {
    #pragma unroll
    for (int bb = 0; bb < 19; ++bb)
        if (m & (1u << bb)) { ax[bb] += w.x; ay[bb] += w.y; }
}

// D': stream W2 exactly once. Block = (col-slice cs of 1024 cols, row-block rb
// of 128 rows). Thread owns 2 columns x 19 step-accumulators. Rows ascending
// within block; partials reduced in ascending rb order => deterministic.
__global__ void __launch_bounds__(512)
w2_dense_kernel(const float* __restrict__ W2) {
    __shared__ unsigned msk[128];
    int blk = blockIdx.x;
    int cs = blk >> 6;                               // 0..7
    int rb = blk & 63;                               // 0..63
    int tid = threadIdx.x;
    if (tid < 128) msk[tid] = g_mask2[rb * 128 + tid];
    __syncthreads();
    int j = cs * 1024 + tid * 2;
    const float* Wp = W2 + (size_t)rb * 128 * 8192 + j;
    float ax[19], ay[19];
    #pragma unroll
    for (int b = 0; b < 19; ++b) { ax[b] = 0.f; ay[b] = 0.f; }
    for (int r = 0; r < 128; r += 8) {
        const float* p = Wp + (size_t)r * 8192;
        f32x2 w0, w1, w2, w3, w4, w5, w6, w7;
        GLD2(w0, p);                GLD2(w1, p + 8192);
        GLD2(w2, p + 2 * 8192);     GLD2(w3, p + 3 * 8192);
        GLD2(w4, p + 4 * 8192);     GLD2(w5, p + 5 * 8192);
        GLD2(w6, p + 6 * 8192);     GLD2(w7, p + 7 * 8192);
        WAIT8(w0, w1, w2, w3, w4, w5, w6, w7);
        accrow(w0, __builtin_amdgcn_readfirstlane(msk[r    ]), ax, ay);
        accrow(w1, __builtin_amdgcn_readfirstlane(msk[r + 1]), ax, ay);
        accrow(w2, __builtin_amdgcn_readfirstlane(msk[r + 2]), ax, ay);
        accrow(w3, __builtin_amdgcn_readfirstlane(msk[r + 3]), ax, ay);
        accrow(w4, __builtin_amdgcn_readfirstlane(msk[r + 4]), ax, ay);
        accrow(w5, __builtin_amdgcn_readfirstlane(msk[r + 5]), ax, ay);
        accrow(w6, __builtin_amdgcn_readfirstlane(msk[r + 6]), ax, ay);
        accrow(w7, __builtin_amdgcn_readfirstlane(msk[r + 7]), ax, ay);
    }
    #pragma unroll
    for (int b = 0; b < 19; ++b)
        *(f32x2*)&g_part2[rb][b][j] = (f32x2){ax[b], ay[b]};
}

// R: reduce the 64 row-block partials (ascending rb) -> g_sum2[t].
__global__ void __launch_bounds__(512)
w2_reduce_kernel() {
    int b = blockIdx.x;                              // 19 t x 16 col-chunks
    int t = 1 + b / 16;
    int j = (b % 16) * 512 + threadIdx.x;
    float s = 0.f;
    #pragma unroll 8
    for (int rb = 0; rb < 64; ++rb)
        s += g_part2[rb][t - 1][j];
    g_sum2[t][j] = s;
}

// Kernel F1: per-step W3 gather sums (19 parallel blocks, one per step).
__global__ void __launch_bounds__(512)
w3_sums_kernel(const float* __restrict__ W3,
               const unsigned long long* __restrict__ s2_bits) {
    __shared__ SMem sm;
    int t = blockIdx.x + 1;                          // 1..19
    int tid = threadIdx.x;
    int count = compact_par<128>(s2_bits + (size_t)(t - 1) * 128, sm);
    int col = tid & 15, g = tid >> 4;                // g 0..31
    float acc = 0.f;
    if (col < 10) {
        for (int k = g; k < count; k += 32)
            acc += W3[(size_t)sm.list[k] * 10 + col];
    }
    sm.partials[g * 16 + col] = acc;
    __syncthreads();
    if (tid < 10) {
        float s = 0.f;
        for (int gg = 0; gg < 32; ++gg) s += sm.partials[gg * 16 + tid];
        g_sum3[t][tid] = s;
    }
}

// Kernel F2: 10-neuron LIF chain over the 19 step sums (single wave).
__global__ void w3_lif_kernel(float* __restrict__ out) {
    int tid = threadIdx.x;
    if (tid < 10) {
        float m = 0.f;
        for (int t = 1; t < TSTEPS; ++t) {
            float v = m + g_sum3[t][tid];
            bool fire = (v >= THRESV);
            if (fire) v -= THRESV;
            m = fire ? v : v * DECAYV;
            out[(t + 1) * 10 + tid] = fire ? 1.f : 0.f;
        }
    }
}

extern "C" void kernel_launch(void* const* d_in, const int* in_sizes, int n_in,
                              void* d_out, int out_size, void* d_ws, size_t ws_size,
                              hipStream_t stream) {
    const float* image = (const float*)d_in[0];
    const float* W1 = (const float*)d_in[1];
    const float* W2 = (const float*)d_in[2];
    const float* W3 = (const float*)d_in[3];
    float* out = (float*)d_out;

    char* ws = (char*)d_ws;
    unsigned long long* s_in_bits = (unsigned long long*)ws;            // [20][48]
    unsigned long long* s1_bits = (unsigned long long*)(ws + 7680);     // [20][128]
    unsigned long long* s2_bits = (unsigned long long*)(ws + 28160);    // [20][128]

    // zero bit buffers (s2_bits[0] must be zero) + output (rows 0,1 stay zero)
    hipMemsetAsync(d_ws, 0, 48640, stream);
    hipMemsetAsync(d_out, 0, (size_t)out_size * sizeof(float), stream);

    // A: input spikes for all steps
    snn_input_kernel<<<12, 256, 0, stream>>>(image, s_in_bits);
    // L1: firing lists for input spikes
    build_lists1_kernel<<<TSTEPS, 512, 0, stream>>>(s_in_bits);
    // B: all W1 gather sums (sparse, bitwise-identical to r19)
    w1_sums_kernel<<<32 * TSTEPS, 512, 0, stream>>>(W1);
    // C: LIF chain layer 1 -> s1 bits
    lif_chain_kernel<<<16, 512, 0, stream>>>(0, s1_bits, 0);
    // M2: per-row fire masks for dense W2
    build_mask2_kernel<<<16, 512, 0, stream>>>(s1_bits);
    // D': dense single-pass W2 accumulation (reads W2 exactly once)
    w2_dense_kernel<<<8 * 64, 512, 0, stream>>>(W2);
    // R: reduce row-block partials -> g_sum2
    w2_reduce_kernel<<<19 * 16, 512, 0, stream>>>();
    // E: LIF chain layer 2 -> s2 bits
    lif_chain_kernel<<<16, 512, 0, stream>>>(1, s2_bits, 1);
    // F1: per-step W3 gather sums
    w3_sums_kernel<<<TSTEPS - 1, 512, 0, stream>>>(W3, s2_bits);
    // F2: 10-neuron LIF chain -> output rows
    w3_lif_kernel<<<1, 64, 0, stream>>>(out);
}

// Round 21
// 177.590 us; speedup vs baseline: 2.8315x; 1.3325x over previous
//
#include <hip/hip_runtime.h>

#define TSTEPS 20
#define THRESV 1.0f
#define DECAYV 0.9375f

typedef float f32x4 __attribute__((ext_vector_type(4)));
typedef float f32x2 __attribute__((ext_vector_type(2)));

// Per-step gather sums (separated from the sequential LIF chains).
__device__ float g_sum1[TSTEPS][8192];   // 640 KB
__device__ float g_sum2[TSTEPS][8192];   // 640 KB ([0] unused)
__device__ float g_sum3[TSTEPS][16];     // [0] unused

// Dense paths: per-row fire masks + row-block partials.
__device__ unsigned g_mask1[3072];       // 20-bit masks (input spikes)
__device__ float g_part1[32][20][8192];  // 21 MB  (rb = 96-row blocks)
__device__ unsigned g_mask2[8192];       // 19-bit masks (layer-1 spikes)
__device__ float g_part2[64][19][8192];  // 40 MB  (rb = 128-row blocks)

// ws byte layout:
//   [0,      7680)   u64 s_in_bits[20][48]
//   [7680,  28160)   u64 s1_bits[20][128]
//   [28160, 48640)   u64 s2_bits[20][128]   (s2_bits[0] stays zero via memset)

__global__ void snn_input_kernel(const float* __restrict__ image,
                                 unsigned long long* __restrict__ s_in_bits) {
    int i = blockIdx.x * 256 + threadIdx.x;   // 0..3071
    float img = image[i];
    float mi = 0.f;
    int word = i >> 6, lane = i & 63;
    for (int t = 0; t < TSTEPS; ++t) {
        mi += img;
        bool fire = (mi >= THRESV);
        if (fire) mi -= THRESV;
        unsigned long long bm = __ballot(fire);
        if (lane == 0) s_in_bits[t * 48 + word] = bm;
    }
}

struct __align__(16) SMem {
    unsigned short list[8192];      // firing-row indices (W3 path)
    float partials[512];            // [32][16] (W3 path)
    unsigned long long bw[128];
    unsigned pc[128];
    int cntp;
};

// Deterministic parallel compaction (ascending list order, bitwise-stable).
template <int NW>
__device__ __forceinline__ int compact_par(const unsigned long long* bits, SMem& sm) {
    int tid = threadIdx.x;
    if (tid < NW) {
        unsigned long long w = bits[tid];
        sm.bw[tid] = w;
        sm.pc[tid] = (unsigned)__popcll(w);
    }
    __syncthreads();
    constexpr int WPW = NW / 8;
    int wave = tid >> 6, lane = tid & 63;
    int w0 = wave * WPW;
    int base = 0;
    for (int i = lane; i < w0; i += 64) base += (int)sm.pc[i];
    #pragma unroll
    for (int off = 1; off < 64; off <<= 1) base += __shfl_xor(base, off);
    if (wave == 0) {
        int tot = 0;
        for (int i = lane; i < NW; i += 64) tot += (int)sm.pc[i];
        #pragma unroll
        for (int off = 1; off < 64; off <<= 1) tot += __shfl_xor(tot, off);
        if (lane == 0) sm.cntp = tot;
    }
    for (int i = 0; i < WPW; ++i) {
        unsigned long long w = sm.bw[w0 + i];
        if ((w >> lane) & 1ull) {
            int pos = base + __popcll(w & ((1ull << lane) - 1ull));
            sm.list[pos] = (unsigned short)(((w0 + i) << 6) + lane);
        }
        base += __popcll(w);
    }
    __syncthreads();
    return sm.cntp;
}

#define GLD2(dst, ptr) \
    asm volatile("global_load_dwordx2 %0, %1, off" : "=v"(dst) : "v"(ptr))
#define WAIT8(a0,a1,a2,a3,a4,a5,a6,a7) \
    asm volatile("s_waitcnt vmcnt(0)" \
        : "+v"(a0),"+v"(a1),"+v"(a2),"+v"(a3),"+v"(a4),"+v"(a5),"+v"(a6),"+v"(a7))

// ---- Dense W1 path ----
// M1: per-row 20-bit masks (bit t = input spike at step t -> feeds sum1[t]).
__global__ void __launch_bounds__(512)
build_mask1_kernel(const unsigned long long* __restrict__ s_in_bits) {
    int i = blockIdx.x * 512 + threadIdx.x;          // 0..3071
    if (i < 3072) {
        unsigned m = 0;
        #pragma unroll
        for (int t = 0; t < 20; ++t)
            m |= (unsigned)((s_in_bits[(size_t)t * 48 + (i >> 6)] >> (i & 63)) & 1ull) << t;
        g_mask1[i] = m;
    }
}

__device__ __forceinline__ void accrow20(f32x2 w, unsigned m, float* ax, float* ay) {
    #pragma unroll
    for (int bb = 0; bb < 20; ++bb)
        if (m & (1u << bb)) { ax[bb] += w.x; ay[bb] += w.y; }
}

// B': stream W1 exactly once. Block = (col-slice cs of 1024 cols, row-block rb
// of 96 rows). Thread owns 2 cols x 20 step-accumulators. Rows ascending within
// block; partials reduced ascending rb => canonical rows-ascending total order.
__global__ void __launch_bounds__(512)
w1_dense_kernel(const float* __restrict__ W1) {
    __shared__ unsigned msk[96];
    int blk = blockIdx.x;
    int cs = blk >> 5;                               // 0..7
    int rb = blk & 31;                               // 0..31
    int tid = threadIdx.x;
    if (tid < 96) msk[tid] = g_mask1[rb * 96 + tid];
    __syncthreads();
    int j = cs * 1024 + tid * 2;
    const float* Wp = W1 + (size_t)rb * 96 * 8192 + j;
    float ax[20], ay[20];
    #pragma unroll
    for (int b = 0; b < 20; ++b) { ax[b] = 0.f; ay[b] = 0.f; }
    for (int r = 0; r < 96; r += 8) {
        const float* p = Wp + (size_t)r * 8192;
        f32x2 w0, w1, w2, w3, w4, w5, w6, w7;
        GLD2(w0, p);                GLD2(w1, p + 8192);
        GLD2(w2, p + 2 * 8192);     GLD2(w3, p + 3 * 8192);
        GLD2(w4, p + 4 * 8192);     GLD2(w5, p + 5 * 8192);
        GLD2(w6, p + 6 * 8192);     GLD2(w7, p + 7 * 8192);
        WAIT8(w0, w1, w2, w3, w4, w5, w6, w7);
        accrow20(w0, __builtin_amdgcn_readfirstlane(msk[r    ]), ax, ay);
        accrow20(w1, __builtin_amdgcn_readfirstlane(msk[r + 1]), ax, ay);
        accrow20(w2, __builtin_amdgcn_readfirstlane(msk[r + 2]), ax, ay);
        accrow20(w3, __builtin_amdgcn_readfirstlane(msk[r + 3]), ax, ay);
        accrow20(w4, __builtin_amdgcn_readfirstlane(msk[r + 4]), ax, ay);
        accrow20(w5, __builtin_amdgcn_readfirstlane(msk[r + 5]), ax, ay);
        accrow20(w6, __builtin_amdgcn_readfirstlane(msk[r + 6]), ax, ay);
        accrow20(w7, __builtin_amdgcn_readfirstlane(msk[r + 7]), ax, ay);
    }
    #pragma unroll
    for (int b = 0; b < 20; ++b)
        *(f32x2*)&g_part1[rb][b][j] = (f32x2){ax[b], ay[b]};
}

// R1: reduce the 32 row-block partials (ascending rb) -> g_sum1[t].
__global__ void __launch_bounds__(512)
w1_reduce_kernel() {
    int b = blockIdx.x;                              // 20 t x 16 col-chunks
    int t = b / 16;
    int j = (b % 16) * 512 + threadIdx.x;
    float s = 0.f;
    #pragma unroll 8
    for (int rb = 0; rb < 32; ++rb)
        s += g_part1[rb][t][j];
    g_sum1[t][j] = s;
}

// Kernels C/E: sequential LIF chain per neuron.
__global__ void __launch_bounds__(512)
lif_chain_kernel(int which,
                 unsigned long long* __restrict__ bits_out,  // [TSTEPS][128]
                 int tstart) {
    const float* sums = (which == 0) ? &g_sum1[0][0] : &g_sum2[0][0];
    int j = blockIdx.x * 512 + threadIdx.x;          // 0..8191
    int lane = threadIdx.x & 63;
    float m = 0.f;
    for (int t = tstart; t < TSTEPS; ++t) {
        float v = m + sums[(size_t)t * 8192 + j];
        bool fire = (v >= THRESV);
        if (fire) v -= THRESV;
        m = fire ? v : v * DECAYV;
        unsigned long long bm = __ballot(fire);
        if (lane == 0) bits_out[(size_t)t * 128 + (j >> 6)] = bm;
    }
}

// ---- Dense W2 path (r20, validated) ----
__global__ void __launch_bounds__(512)
build_mask2_kernel(const unsigned long long* __restrict__ s1_bits) {
    int i = blockIdx.x * 512 + threadIdx.x;          // 0..8191
    unsigned m = 0;
    #pragma unroll
    for (int b = 0; b < 19; ++b)
        m |= (unsigned)((s1_bits[(size_t)b * 128 + (i >> 6)] >> (i & 63)) & 1ull) << b;
    g_mask2[i] = m;
}

__device__ __forceinline__ void accrow(f32x2 w, unsigned m, float* ax, float* ay) {
    #pragma unroll
    for (int bb = 0; bb < 19; ++bb)
        if (m & (1u << bb)) { ax[bb] += w.x; ay[bb] += w.y; }
}

__global__ void __launch_bounds__(512)
w2_dense_kernel(const float* __restrict__ W2) {
    __shared__ unsigned msk[128];
    int blk = blockIdx.x;
    int cs = blk >> 6;                               // 0..7
    int rb = blk & 63;                               // 0..63
    int tid = threadIdx.x;
    if (tid < 128) msk[tid] = g_mask2[rb * 128 + tid];
    __syncthreads();
    int j = cs * 1024 + tid * 2;
    const float* Wp = W2 + (size_t)rb * 128 * 8192 + j;
    float ax[19], ay[19];
    #pragma unroll
    for (int b = 0; b < 19; ++b) { ax[b] = 0.f; ay[b] = 0.f; }
    for (int r = 0; r < 128; r += 8) {
        const float* p = Wp + (size_t)r * 8192;
        f32x2 w0, w1, w2, w3, w4, w5, w6, w7;
        GLD2(w0, p);                GLD2(w1, p + 8192);
        GLD2(w2, p + 2 * 8192);     GLD2(w3, p + 3 * 8192);
        GLD2(w4, p + 4 * 8192);     GLD2(w5, p + 5 * 8192);
        GLD2(w6, p + 6 * 8192);     GLD2(w7, p + 7 * 8192);
        WAIT8(w0, w1, w2, w3, w4, w5, w6, w7);
        accrow(w0, __builtin_amdgcn_readfirstlane(msk[r    ]), ax, ay);
        accrow(w1, __builtin_amdgcn_readfirstlane(msk[r + 1]), ax, ay);
        accrow(w2, __builtin_amdgcn_readfirstlane(msk[r + 2]), ax, ay);
        accrow(w3, __builtin_amdgcn_readfirstlane(msk[r + 3]), ax, ay);
        accrow(w4, __builtin_amdgcn_readfirstlane(msk[r + 4]), ax, ay);
        accrow(w5, __builtin_amdgcn_readfirstlane(msk[r + 5]), ax, ay);
        accrow(w6, __builtin_amdgcn_readfirstlane(msk[r + 6]), ax, ay);
        accrow(w7, __builtin_amdgcn_readfirstlane(msk[r + 7]), ax, ay);
    }
    #pragma unroll
    for (int b = 0; b < 19; ++b)
        *(f32x2*)&g_part2[rb][b][j] = (f32x2){ax[b], ay[b]};
}

__global__ void __launch_bounds__(512)
w2_reduce_kernel() {
    int b = blockIdx.x;                              // 19 t x 16 col-chunks
    int t = 1 + b / 16;
    int j = (b % 16) * 512 + threadIdx.x;
    float s = 0.f;
    #pragma unroll 8
    for (int rb = 0; rb < 64; ++rb)
        s += g_part2[rb][t - 1][j];
    g_sum2[t][j] = s;
}

// Kernel F1: per-step W3 gather sums (19 parallel blocks, one per step).
__global__ void __launch_bounds__(512)
w3_sums_kernel(const float* __restrict__ W3,
               const unsigned long long* __restrict__ s2_bits) {
    __shared__ SMem sm;
    int t = blockIdx.x + 1;                          // 1..19
    int tid = threadIdx.x;
    int count = compact_par<128>(s2_bits + (size_t)(t - 1) * 128, sm);
    int col = tid & 15, g = tid >> 4;                // g 0..31
    float acc = 0.f;
    if (col < 10) {
        for (int k = g; k < count; k += 32)
            acc += W3[(size_t)sm.list[k] * 10 + col];
    }
    sm.partials[g * 16 + col] = acc;
    __syncthreads();
    if (tid < 10) {
        float s = 0.f;
        for (int gg = 0; gg < 32; ++gg) s += sm.partials[gg * 16 + tid];
        g_sum3[t][tid] = s;
    }
}

// Kernel F2: 10-neuron LIF chain over the 19 step sums (single wave).
__global__ void w3_lif_kernel(float* __restrict__ out) {
    int tid = threadIdx.x;
    if (tid < 10) {
        float m = 0.f;
        for (int t = 1; t < TSTEPS; ++t) {
            float v = m + g_sum3[t][tid];
            bool fire = (v >= THRESV);
            if (fire) v -= THRESV;
            m = fire ? v : v * DECAYV;
            out[(t + 1) * 10 + tid] = fire ? 1.f : 0.f;
        }
    }
}

extern "C" void kernel_launch(void* const* d_in, const int* in_sizes, int n_in,
                              void* d_out, int out_size, void* d_ws, size_t ws_size,
                              hipStream_t stream) {
    const float* image = (const float*)d_in[0];
    const float* W1 = (const float*)d_in[1];
    const float* W2 = (const float*)d_in[2];
    const float* W3 = (const float*)d_in[3];
    float* out = (float*)d_out;

    char* ws = (char*)d_ws;
    unsigned long long* s_in_bits = (unsigned long long*)ws;            // [20][48]
    unsigned long long* s1_bits = (unsigned long long*)(ws + 7680);     // [20][128]
    unsigned long long* s2_bits = (unsigned long long*)(ws + 28160);    // [20][128]

    // zero bit buffers (s2_bits[0] must be zero) + output (rows 0,1 stay zero)
    hipMemsetAsync(d_ws, 0, 48640, stream);
    hipMemsetAsync(d_out, 0, (size_t)out_size * sizeof(float), stream);

    // A: input spikes for all steps
    snn_input_kernel<<<12, 256, 0, stream>>>(image, s_in_bits);
    // M1: per-row fire masks for dense W1
    build_mask1_kernel<<<6, 512, 0, stream>>>(s_in_bits);
    // B': dense single-pass W1 accumulation (reads W1 exactly once)
    w1_dense_kernel<<<8 * 32, 512, 0, stream>>>(W1);
    // R1: reduce row-block partials -> g_sum1
    w1_reduce_kernel<<<20 * 16, 512, 0, stream>>>();
    // C: LIF chain layer 1 -> s1 bits
    lif_chain_kernel<<<16, 512, 0, stream>>>(0, s1_bits, 0);
    // M2: per-row fire masks for dense W2
    build_mask2_kernel<<<16, 512, 0, stream>>>(s1_bits);
    // D': dense single-pass W2 accumulation (reads W2 exactly once)
    w2_dense_kernel<<<8 * 64, 512, 0, stream>>>(W2);
    // R2: reduce row-block partials -> g_sum2
    w2_reduce_kernel<<<19 * 16, 512, 0, stream>>>();
    // E: LIF chain layer 2 -> s2 bits
    lif_chain_kernel<<<16, 512, 0, stream>>>(1, s2_bits, 1);
    // F1: per-step W3 gather sums
    w3_sums_kernel<<<TSTEPS - 1, 512, 0, stream>>>(W3, s2_bits);
    // F2: 10-neuron LIF chain -> output rows
    w3_lif_kernel<<<1, 64, 0, stream>>>(out);
}